// Round 11
// baseline (963.892 us; speedup 1.0000x reference)
//
#include <hip/hip_runtime.h>
#include <hip/hip_bf16.h>
#include <math.h>

typedef __attribute__((ext_vector_type(8))) short bf16x8;
typedef __attribute__((ext_vector_type(4))) float f32x4;
typedef __attribute__((ext_vector_type(4))) short s16x4;
typedef unsigned int u32;
typedef unsigned long long u64;

#define NBATCH 4
#define NPTS   4096
#define NTOT   (NBATCH*NPTS)     // 16384 points
#define NROWS  (NTOT*16)         // 262144 (point,neighbor) rows

__device__ __forceinline__ float bf2f(unsigned short h){
  unsigned int u = ((unsigned int)h) << 16;
  return __builtin_bit_cast(float, u);
}
__device__ __forceinline__ unsigned short f2bf(float f){
  unsigned int u = __builtin_bit_cast(unsigned int, f);
  u += 0x7FFFu + ((u >> 16) & 1u);   // RNE
  return (unsigned short)(u >> 16);
}
__device__ __forceinline__ unsigned short f2bfh(float f){   // HW cvt (RNE, pairs fuse to cvt_pk)
  return __bfloat16_as_ushort(__float2bfloat16(f));
}

#define MFMA(a,b,c) __builtin_amdgcn_mfma_f32_16x16x32_bf16((a),(b),(c),0,0,0)

typedef u32 __attribute__((address_space(1))) gas_u32;
typedef u32 __attribute__((address_space(3))) las_u32;
__device__ __forceinline__ void gl_lds16(const void* g, void* l){
  __builtin_amdgcn_global_load_lds((const gas_u32*)g, (las_u32*)l, 16, 0, 0);
}

// wave-internal LDS ordering fence (rule #18 pattern)
__device__ __forceinline__ void wfence(){
  asm volatile("s_waitcnt lgkmcnt(0)" ::: "memory");
  __builtin_amdgcn_sched_barrier(0);
}

// ---------------- prep: features -> bf16 ----------------
__global__ __launch_bounds__(256) void k_convert(const float* __restrict__ x,
                                                 unsigned short* __restrict__ xb, int n){
  int i = (blockIdx.x * 256 + threadIdx.x) * 4;
  if (i < n){
    float4 v = *(const float4*)(x + i);
    s16x4 o;
    o[0] = (short)f2bf(v.x); o[1] = (short)f2bf(v.y);
    o[2] = (short)f2bf(v.z); o[3] = (short)f2bf(v.w);
    *(s16x4*)(xb + i) = o;
  }
}

// ---------------- prep: xyz -> float4 (x,y,z,|p|^2) ----------------
__global__ __launch_bounds__(256) void k_xyzw(const float* __restrict__ xyz,
                                              float4* __restrict__ xyzw){
  int i = blockIdx.x * 256 + threadIdx.x;   // 16384
  float x = xyz[i*3], y = xyz[i*3+1], z = xyz[i*3+2];
  xyzw[i] = make_float4(x, y, z, x*x + y*y + z*z);
}

// ---------------- prep: transposed bf16 weight copies ----------------
__global__ __launch_bounds__(256) void k_prep_mats(
    const float* __restrict__ scw, const float* __restrict__ g2,
    const float* __restrict__ fc2, const float* __restrict__ W2,
    const float* __restrict__ scb,
    unsigned short* __restrict__ qkv2T, unsigned short* __restrict__ g2sT,
    unsigned short* __restrict__ fc2T, unsigned short* __restrict__ BposT,
    float* __restrict__ cvec){
  int c = blockIdx.x, d = threadIdx.x;
  qkv2T[(768+c)*256 + d] = f2bf(scw[d*256 + c]);             // sc^T
  g2sT[c*256 + d]        = f2bf(g2[d*256 + c] * 0.0625f);    // fold 1/sqrt(DM)=1/16
  fc2T[c*256 + d]        = f2bf(fc2[d*256 + c]);
  BposT[(256+c)*256 + d] = f2bf(W2[d*256 + c]);              // W2^T (pe)
  if (d == 0) cvec[768 + c] = scb[c];
}

// ---------------- prep stage 1: Wqg = wq@g1, Wkg = wk@g1, W2g1, c1 ----------------
__global__ __launch_bounds__(256) void k_prep_gemm(
    const float* __restrict__ wq, const float* __restrict__ wk,
    const float* __restrict__ g1, const float* __restrict__ W2,
    const float* __restrict__ b2d, const float* __restrict__ gb1,
    unsigned short* __restrict__ tmpWq, unsigned short* __restrict__ tmpWk,
    unsigned short* __restrict__ BposT, float* __restrict__ c1){
  int c = threadIdx.x, bid = blockIdx.x;
  if (bid < 256){
    int d = bid; float acc = 0.f;
    for (int e=0;e<256;e++) acc += wq[d*256+e]*g1[e*256+c];
    tmpWq[c*256 + d] = f2bf(acc);
  } else if (bid < 512){
    int d = bid-256; float acc = 0.f;
    for (int e=0;e<256;e++) acc += wk[d*256+e]*g1[e*256+c];
    tmpWk[c*256 + d] = f2bf(acc);
  } else if (bid < 768){
    int d = bid-512; float acc = 0.f;
    for (int e=0;e<256;e++) acc += W2[d*256+e]*g1[e*256+c];
    BposT[c*256 + d] = f2bf(acc);
  } else {
    float acc = 0.f;
    for (int e=0;e<256;e++) acc += b2d[e]*g1[e*256+c];
    c1[c] = acc + gb1[c];
  }
}

// ---------------- prep stage 2: fold fc1 into QKV ----------------
__global__ __launch_bounds__(256) void k_prep_gemm2(
    const float* __restrict__ fc1w, const float* __restrict__ fc1b,
    const float* __restrict__ wv,
    const unsigned short* __restrict__ tmpWq, const unsigned short* __restrict__ tmpWk,
    unsigned short* __restrict__ qkv2T, float* __restrict__ cvec){
  int c = threadIdx.x, bid = blockIdx.x;
  if (bid < 256){
    int d = bid; float acc = 0.f;
    for (int e=0;e<256;e++) acc += fc1w[d*256+e]*bf2f(tmpWq[c*256+e]);
    qkv2T[c*256 + d] = f2bf(acc);
  } else if (bid < 512){
    int d = bid-256; float acc = 0.f;
    for (int e=0;e<256;e++) acc += fc1w[d*256+e]*bf2f(tmpWk[c*256+e]);
    qkv2T[(256+c)*256 + d] = f2bf(acc);
  } else if (bid < 768){
    int d = bid-512; float acc = 0.f;
    for (int e=0;e<256;e++) acc += fc1w[d*256+e]*wv[e*256+c];
    qkv2T[(512+c)*256 + d] = f2bf(acc);
  } else {
    float aq=0.f, ak=0.f, av=0.f;
    for (int e=0;e<256;e++){
      float fb = fc1b[e];
      aq += fb*bf2f(tmpWq[c*256+e]);
      ak += fb*bf2f(tmpWk[c*256+e]);
      av += fb*wv[e*256+c];
    }
    cvec[c] = aq; cvec[256+c] = ak; cvec[512+c] = av;
  }
}

// ======== kNN: radix rank-select, 8-bit hi-keys cached in 16 VGPRs ========
__device__ __forceinline__ u32 fmap(float d){
  u32 u = __builtin_bit_cast(u32, d);
  return ((int)u < 0) ? ~u : (u | 0x80000000u);
}

__device__ __forceinline__ void find_thresh(const int* hist, int lane, int need,
                                            int* e_out, int* c_out){
  int h0 = hist[lane*4], h1 = hist[lane*4+1], h2 = hist[lane*4+2], h3 = hist[lane*4+3];
  int ps = h0 + h1 + h2 + h3;
  int incl = ps;
  #pragma unroll
  for (int d = 1; d < 64; d <<= 1){
    int tv = __shfl_up(incl, d, 64);
    if (lane >= d) incl += tv;
  }
  int excl = incl - ps;
  int b0 = excl, b1 = excl + h0, b2 = b1 + h1, b3 = b2 + h2;
  bool f0 = (b0 < need) && (b0 + h0 >= need);
  bool f1 = (b1 < need) && (b1 + h1 >= need);
  bool f2 = (b2 < need) && (b2 + h2 >= need);
  bool f3 = (b3 < need) && (b3 + h3 >= need);
  int e_loc = f0 ? lane*4 : f1 ? lane*4+1 : f2 ? lane*4+2 : lane*4+3;
  int c_loc = f0 ? b0 : f1 ? b1 : f2 ? b2 : b3;
  u64 mk = __ballot(f0 | f1 | f2 | f3);
  int wl = __ffsll(mk) - 1;
  *e_out = __shfl(e_loc, wl, 64);
  *c_out = __shfl(c_loc, wl, 64);
}

__device__ __forceinline__ void find_thresh4(const int* hA, int lane, int need,
                                             int* e_out, int* c_out){
  int h[4];
  #pragma unroll
  for (int j=0;j<4;j++){
    int bin = lane*4+j;
    h[j] = hA[bin]
         + hA[256 + ((bin+8)&255)]
         + hA[512 + ((bin+16)&255)]
         + hA[768 + ((bin+24)&255)];
  }
  int ps = h[0] + h[1] + h[2] + h[3];
  int incl = ps;
  #pragma unroll
  for (int d = 1; d < 64; d <<= 1){
    int tv = __shfl_up(incl, d, 64);
    if (lane >= d) incl += tv;
  }
  int excl = incl - ps;
  int b0 = excl, b1 = excl + h[0], b2 = b1 + h[1], b3 = b2 + h[2];
  bool f0 = (b0 < need) && (b0 + h[0] >= need);
  bool f1 = (b1 < need) && (b1 + h[1] >= need);
  bool f2 = (b2 < need) && (b2 + h[2] >= need);
  bool f3 = (b3 < need) && (b3 + h[3] >= need);
  int e_loc = f0 ? lane*4 : f1 ? lane*4+1 : f2 ? lane*4+2 : lane*4+3;
  int c_loc = f0 ? b0 : f1 ? b1 : f2 ? b2 : b3;
  u64 mk = __ballot(f0 | f1 | f2 | f3);
  int wl = __ffsll(mk) - 1;
  *e_out = __shfl(e_loc, wl, 64);
  *c_out = __shfl(c_loc, wl, 64);
}

__global__ __launch_bounds__(256) void k_knn(const float4* __restrict__ xyzw,
                                             int* __restrict__ gidxbuf,
                                             float4* __restrict__ relbuf){
  __shared__ int histA[4][1024];    // 4 waves x 4 rotated copies x 256 bins
  __shared__ int histB[4][256];
  __shared__ u32 lstU[4][64];
  __shared__ int lstM[4][64];

  int t = threadIdx.x, lane = t & 63, wv = t >> 6;
  int widx = blockIdx.x * 4 + wv;          // 0..16383
  int b = widx >> 12, n = widx & 4095;
  const float4* xb = xyzw + (size_t)b * NPTS;
  float4 P = xb[n];
  float x2n = P.w;
  int* hA = histA[wv]; int* hB = histB[wv];

  #pragma unroll
  for (int j = 0; j < 16; j++) hA[lane*16+j] = 0;
  #pragma unroll
  for (int j = 0; j < 4; j++)  hB[lane*4+j] = 0;
  wfence();

  int cp = lane >> 4;                      // sub-copy 0..3 (16 lanes each)
  int cpoff = cp*256, cprot = cp*8;

  // pass 1: distances ONCE; hi byte packed 4-per-u32 (STATIC idx); coarse hist
  u32 khi[16];
  #pragma unroll
  for (int it = 0; it < 16; it++){
    u32 pack = 0;
    #pragma unroll
    for (int q = 0; q < 4; q++){
      float4 Q = xb[it*256 + q*64 + lane];
      float d = x2n + Q.w - 2.0f*(P.x*Q.x + P.y*Q.y + P.z*Q.z);
      u32 hi = fmap(d) >> 24;
      pack |= hi << (q*8);
      atomicAdd(&hA[cpoff + (((int)hi + cprot)&255)], 1);
    }
    khi[it] = pack;
  }
  wfence();
  int e1, c0;
  find_thresh4(hA, lane, 16, &e1, &c0);

  // pass 2: refine within bin e1 — recompute distance ONLY for hi==e1 (rare)
  #pragma unroll
  for (int it = 0; it < 16; it++){
    #pragma unroll
    for (int q = 0; q < 4; q++){
      int hi = (int)((khi[it] >> (q*8)) & 0xFFu);
      if (hi == e1){
        float4 Q = xb[it*256 + q*64 + lane];
        u32 u = fmap(x2n + Q.w - 2.0f*(P.x*Q.x + P.y*Q.y + P.z*Q.z));
        atomicAdd(&hB[(u >> 16) & 0xFF], 1);
      }
    }
  }
  wfence();
  int m1, cc;
  find_thresh(hB, lane, 16 - c0, &m1, &cc);
  int c1 = c0 + cc;                        // definite members, < 16

  // pass 3: key scan (registers); full distance only for boundary bin
  int base = 0, Lc = 0;
  size_t orow = (size_t)widx * 16;
  #pragma unroll
  for (int it = 0; it < 16; it++){
    #pragma unroll
    for (int q = 0; q < 4; q++){
      int m = it*256 + q*64 + lane;
      int hi = (int)((khi[it] >> (q*8)) & 0xFFu);
      bool eqE = (hi == e1);
      u32 u = 0; int mid = 256;            // sentinel > any real mid
      if (eqE){
        float4 Q = xb[m];
        u = fmap(x2n + Q.w - 2.0f*(P.x*Q.x + P.y*Q.y + P.z*Q.z));
        mid = (int)((u >> 16) & 0xFF);
      }
      bool def = (hi < e1) || (eqE && mid < m1);
      bool bnd = eqE && (mid == m1);
      u64 mkd = __ballot(def);
      if (def){
        int slot = base + __popcll(mkd & ((1ULL << lane) - 1ULL));
        float4 Q = xb[m];
        gidxbuf[orow + slot] = b*NPTS + m;
        relbuf[orow + slot]  = make_float4(P.x - Q.x, P.y - Q.y, P.z - Q.z, 0.f);
      }
      base += __popcll(mkd);
      u64 mkb = __ballot(bnd);
      if (bnd){
        int sl = Lc + __popcll(mkb & ((1ULL << lane) - 1ULL));
        if (sl < 64){ lstU[wv][sl] = u; lstM[wv][sl] = m; }
      }
      Lc += __popcll(mkb);
    }
  }
  wfence();
  if (Lc > 64) Lc = 64;

  // pop the remaining 16-c1 smallest (u, idx) lexicographically (== top_k tie-break)
  int r2 = 16 - c1;
  u32 lu = (lane < Lc) ? lstU[wv][lane] : 0xFFFFFFFFu;
  int lm = (lane < Lc) ? lstM[wv][lane] : 0x7FFFFFFF;
  bool popped = false;
  for (int r = 0; r < r2; r++){
    u32 ku = popped ? 0xFFFFFFFFu : lu;
    int km = popped ? 0x7FFFFFFF : lm;
    #pragma unroll
    for (int off = 32; off >= 1; off >>= 1){
      u32 ou = __shfl_xor(ku, off, 64);
      int om = __shfl_xor(km, off, 64);
      if (ou < ku || (ou == ku && om < km)){ ku = ou; km = om; }
    }
    bool mine = !popped && (lane < Lc) && (lu == ku) && (lm == km);
    u64 mk = __ballot(mine);
    int wl = __ffsll(mk) - 1;
    if (lane == wl){
      popped = true;
      float4 Q = xb[km];
      gidxbuf[orow + c1 + r] = b*NPTS + km;
      relbuf[orow + c1 + r]  = make_float4(P.x - Q.x, P.y - Q.y, P.z - Q.z, 0.f);
    }
  }
}

// ============ unified GEMM: 512 thr (8 waves, 2x4), BM=128, BN=256, BK=32 ============
// MODE 0: QKV  A=Xb  BT=qkv2T  grid.y=4 (one 256-col buffer per y): qg|kg|v|sc (+cvec)
// MODE 2: G2   A=on-the-fly H  BT=BposT grid.y=2: y0 -> a1, y1 -> vpe
// MODE 3: G3   A=a1  BT=g2sT   grid.y=1: softmax+combine(vpe) -> res
// MODE 4: FIN  A=res BT=fc2T   grid.y=1: fp32 out (+fc2b+sc)
template<int MODE>
__global__ __launch_bounds__(512) void k_mm(
    const unsigned short* __restrict__ A, const unsigned short* __restrict__ BT,
    int rowbase,
    const float* __restrict__ bias, const float* __restrict__ b2v,
    const unsigned short* __restrict__ qg, const unsigned short* __restrict__ kg,
    const unsigned short* __restrict__ vb,
    const float4* __restrict__ relbuf, const int* __restrict__ gidxbuf,
    const float* __restrict__ W1, const float* __restrict__ b1d,
    unsigned short* __restrict__ o0, unsigned short* __restrict__ o1,
    unsigned short* __restrict__ o2, unsigned short* __restrict__ o3,
    const unsigned short* __restrict__ vper,
    float* __restrict__ fout){
  __shared__ unsigned short As[4096];   // 128 x 32
  __shared__ unsigned short Bs[8192];   // 256 x 32
  __shared__ float4 W1s4[256];          // (w1x,w1y,w1z,b1) per column (MODE 2)
  __shared__ float4 relS[128];
  __shared__ int    gidxS[128];
  __shared__ float  biasS[256];

  int t = threadIdx.x;
  int lane = t & 63, w = t >> 6;
  int wm = w >> 2, wn = w & 3;          // 2 x 4 wave grid
  int lrow = lane & 15, lkg = lane >> 4;
  int bx = blockIdx.x;
  if constexpr (MODE == 2){
    int gx = gridDim.x;
    bx = (bx & 7) * (gx >> 3) + (bx >> 3);   // XCD-aware swizzle (gridDim.x % 8 == 0)
  }
  int m0 = bx * 128, n0 = blockIdx.y * 256;

  float4 rl0 = make_float4(0.f,0.f,0.f,0.f);
  if constexpr (MODE == 2){
    if (t < 128){
      relS[t]  = relbuf[(size_t)rowbase + m0 + t];
      gidxS[t] = gidxbuf[(size_t)rowbase + m0 + t];
    }
    if (t < 256){
      biasS[t] = (blockIdx.y == 0) ? bias[t] : b2v[t];
      W1s4[t] = make_float4(W1[t], W1[256+t], W1[512+t], b1d[t]);
    }
    __syncthreads();
    rl0 = relS[t >> 2];                 // hoisted: loop-invariant across k0
  }
  if constexpr (MODE == 0){
    if (t < 256) biasS[t] = bias[n0 + t];   // K-loop barrier orders this before use
  }

  int sr = t >> 2, sc = (t & 3) * 8;               // staging: row 0..127, col(8 bf16=16B)
  unsigned short* lA  = As + (w << 9);             // wave-uniform LDS bases (1KB/wave)
  unsigned short* lB  = Bs + (w << 9);
  unsigned short* lB2 = Bs + 4096 + (w << 9);
  const unsigned short* gB  = BT + (size_t)(n0 + sr)*256 + sc;
  const unsigned short* gB2 = BT + (size_t)(n0 + 128 + sr)*256 + sc;

  f32x4 acc[4][4] = {};
  for (int k0 = 0; k0 < 256; k0 += 32){
    if constexpr (MODE == 2){
      // compute H tile rows [m0,m0+128) cols [k0,k0+32) on the fly
      int r = t >> 2, h = (t & 3) << 3;
      bf16x8 h0;
      #pragma unroll
      for (int j = 0; j < 8; j++){
        int c = k0 + h + j;
        float4 wa = W1s4[c];
        float x0 = rl0.x*wa.x + rl0.y*wa.y + rl0.z*wa.z + wa.w;
        h0[j] = (short)f2bfh(fmaxf(x0, 0.f));
      }
      *(bf16x8*)&As[r*32 + h] = h0;
    } else {
      const unsigned short* gA = A + (size_t)(m0 + sr)*256 + k0 + sc;
      gl_lds16(gA, lA);
    }
    gl_lds16(gB  + k0, lB);
    gl_lds16(gB2 + k0, lB2);
    __syncthreads();
    bf16x8 af[4], bfr[4];
    #pragma unroll
    for (int fi = 0; fi < 4; fi++)
      af[fi] = *(const bf16x8*)&As[(wm*64 + fi*16 + lrow)*32 + lkg*8];
    #pragma unroll
    for (int nf = 0; nf < 4; nf++)
      bfr[nf] = *(const bf16x8*)&Bs[(wn*64 + nf*16 + lrow)*32 + lkg*8];
    #pragma unroll
    for (int fi = 0; fi < 4; fi++)
      #pragma unroll
      for (int nf = 0; nf < 4; nf++)
        acc[fi][nf] = MFMA(af[fi], bfr[nf], acc[fi][nf]);
    __syncthreads();
  }

  if constexpr (MODE == 0){
    unsigned short* outp = (blockIdx.y==0)?o0:(blockIdx.y==1)?o1:(blockIdx.y==2)?o2:o3;
    #pragma unroll
    for (int fi=0; fi<4; fi++)
      #pragma unroll
      for (int nf=0; nf<4; nf++)
        #pragma unroll
        for (int r=0;r<4;r++){
          int row = m0 + wm*64 + fi*16 + lkg*4 + r;
          int col = wn*64 + nf*16 + lrow;            // 0..255
          outp[(size_t)row*256 + col] = f2bf(acc[fi][nf][r] + biasS[col]);
        }
  } else if constexpr (MODE == 2){
    const bool is_a1 = (blockIdx.y == 0);
    #pragma unroll
    for (int fi=0; fi<4; fi++){
      int g = (rowbase + m0 + wm*64 + fi*16) >> 4;   // point id (16 rows = 1 point)
      #pragma unroll
      for (int nf=0; nf<4; nf++){
        int colg = wn*64 + nf*16 + lrow;             // 0..255
        if (is_a1){
          float qv = bf2f(qg[(size_t)g*256 + colg]) + biasS[colg];   // biasS = c1
          #pragma unroll
          for (int r=0;r<4;r++){
            int rl_ = wm*64 + fi*16 + lkg*4 + r;
            int gi = gidxS[rl_];
            float a1 = acc[fi][nf][r] + qv - bf2f(kg[(size_t)gi*256 + colg]);
            o0[(size_t)(m0 + rl_)*256 + colg] = f2bfh(fmaxf(a1, 0.f));
          }
        } else {
          float bb = biasS[colg];                    // biasS = b2
          #pragma unroll
          for (int r=0;r<4;r++){
            int rl_ = wm*64 + fi*16 + lkg*4 + r;
            int gi = gidxS[rl_];
            float vpe = acc[fi][nf][r] + bb + bf2f(vb[(size_t)gi*256 + colg]);
            o1[(size_t)(m0 + rl_)*256 + colg] = f2bfh(vpe);
          }
        }
      }
    }
  } else if constexpr (MODE == 3){
    #pragma unroll
    for (int fi=0; fi<4; fi++){
      int g = (rowbase + m0 + wm*64 + fi*16) >> 4;
      #pragma unroll
      for (int nf=0; nf<4; nf++){
        int colg = wn*64 + nf*16 + lrow;             // 0..255
        float s[4], e[4];
        #pragma unroll
        for (int r=0;r<4;r++) s[r] = acc[fi][nf][r] + bias[colg]*0.0625f;  // bias = gb2
        float mx = fmaxf(fmaxf(s[0],s[1]), fmaxf(s[2],s[3]));
        mx = fmaxf(mx, __shfl_xor(mx,16,64));
        mx = fmaxf(mx, __shfl_xor(mx,32,64));
        float sm = 0.f;
        #pragma unroll
        for (int r=0;r<4;r++){ e[r] = __expf(s[r]-mx); sm += e[r]; }
        sm += __shfl_xor(sm,16,64);
        sm += __shfl_xor(sm,32,64);
        float rs = 1.f/sm, tsum = 0.f;
        #pragma unroll
        for (int r=0;r<4;r++){
          int rl_ = wm*64 + fi*16 + lkg*4 + r;
          tsum += (e[r]*rs) * bf2f(vper[(size_t)(m0 + rl_)*256 + colg]);
        }
        tsum += __shfl_xor(tsum,16,64);
        tsum += __shfl_xor(tsum,32,64);
        if (lkg == 0) o0[(size_t)g*256 + colg] = f2bf(tsum);
      }
    }
  } else {   // FIN
    #pragma unroll
    for (int fi=0; fi<4; fi++)
      #pragma unroll
      for (int nf=0; nf<4; nf++)
        #pragma unroll
        for (int r=0;r<4;r++){
          int row = m0 + wm*64 + fi*16 + lkg*4 + r;
          int col = wn*64 + nf*16 + lrow;
          fout[(size_t)row*256 + col] = acc[fi][nf][r] + bias[col]
                                      + bf2f(qg[(size_t)row*256 + col]);  // qg slot = scbuf
        }
  }
}

// ---------------- host ----------------
extern "C" void kernel_launch(void* const* d_in, const int* in_sizes, int n_in,
                              void* d_out, int out_size, void* d_ws, size_t ws_size,
                              hipStream_t stream){
  (void)in_sizes; (void)n_in; (void)out_size;
  const float* xyz  = (const float*)d_in[0];
  const float* feat = (const float*)d_in[1];
  const float* W1   = (const float*)d_in[2];
  const float* b1d  = (const float*)d_in[3];
  const float* W2   = (const float*)d_in[4];
  const float* b2d  = (const float*)d_in[5];
  const float* fc1w = (const float*)d_in[6];
  const float* fc1b = (const float*)d_in[7];
  const float* wq   = (const float*)d_in[8];
  const float* wk   = (const float*)d_in[9];
  const float* wv   = (const float*)d_in[10];
  const float* g1   = (const float*)d_in[11];
  const float* gb1  = (const float*)d_in[12];
  const float* g2   = (const float*)d_in[13];
  const float* gb2  = (const float*)d_in[14];
  const float* fc2w = (const float*)d_in[15];
  const float* fc2b = (const float*)d_in[16];
  const float* scw  = (const float*)d_in[17];
  const float* scb  = (const float*)d_in[18];

  char* ws = (char*)d_ws;
  size_t off = 0;
  auto alloc = [&](size_t bytes)->void*{ void* p = ws + off; off += (bytes + 255) & ~(size_t)255; return p; };
  unsigned short* Xb     = (unsigned short*)alloc((size_t)NTOT*256*2);  // reused as res
  unsigned short* qgb    = (unsigned short*)alloc((size_t)NTOT*256*2);
  unsigned short* kgb    = (unsigned short*)alloc((size_t)NTOT*256*2);
  unsigned short* vbb    = (unsigned short*)alloc((size_t)NTOT*256*2);
  unsigned short* scbuf  = (unsigned short*)alloc((size_t)NTOT*256*2);
  int*            gidxbuf= (int*)alloc((size_t)NROWS*4);
  float4*         relbuf = (float4*)alloc((size_t)NROWS*16);
  float4*         xyzw   = (float4*)alloc((size_t)NTOT*16);
  unsigned short* qkv2T  = (unsigned short*)alloc(1024*256*2);
  unsigned short* tmpWq  = (unsigned short*)alloc(256*256*2);
  unsigned short* tmpWk  = (unsigned short*)alloc(256*256*2);
  unsigned short* BposT  = (unsigned short*)alloc(512*256*2);
  unsigned short* g2sT   = (unsigned short*)alloc(256*256*2);
  unsigned short* fc2T   = (unsigned short*)alloc(256*256*2);
  float*          c1     = (float*)alloc(256*4);
  float*          cvec   = (float*)alloc(1024*4);
  unsigned short* res    = Xb;

  // adaptive chunk: a1 + vpe cost CR*1024 bytes (single chunk if ws allows)
  int CR = NROWS;
  while (CR > 16384 && off + (size_t)CR*1024 > ws_size) CR >>= 1;
  unsigned short* a1buf  = (unsigned short*)alloc((size_t)CR*256*2);
  unsigned short* vpebuf = (unsigned short*)alloc((size_t)CR*256*2);

  k_convert<<<4096, 256, 0, stream>>>(feat, Xb, NTOT*256);
  k_xyzw<<<64, 256, 0, stream>>>(xyz, xyzw);
  k_prep_mats<<<256, 256, 0, stream>>>(scw, g2, fc2w, W2, scb, qkv2T, g2sT, fc2T, BposT, cvec);
  k_prep_gemm<<<769, 256, 0, stream>>>(wq, wk, g1, W2, b2d, gb1, tmpWq, tmpWk, BposT, c1);
  k_prep_gemm2<<<769, 256, 0, stream>>>(fc1w, fc1b, wv, tmpWq, tmpWk, qkv2T, cvec);
  k_knn<<<4096, 256, 0, stream>>>(xyzw, gidxbuf, relbuf);

  k_mm<0><<<dim3(128, 4), 512, 0, stream>>>(Xb, qkv2T, 0, cvec, nullptr,
      nullptr, nullptr, nullptr, nullptr, nullptr, nullptr, nullptr,
      qgb, kgb, vbb, scbuf, nullptr, nullptr);

  for (int c0 = 0; c0 < NROWS; c0 += CR){
    k_mm<2><<<dim3(CR/128, 2), 512, 0, stream>>>(nullptr, BposT, c0, c1, b2d,
        qgb, kgb, vbb, relbuf, gidxbuf, W1, b1d,
        a1buf, vpebuf, nullptr, nullptr, nullptr, nullptr);
    k_mm<3><<<dim3(CR/128, 1), 512, 0, stream>>>(a1buf, g2sT, c0, gb2, nullptr,
        nullptr, nullptr, nullptr, nullptr, nullptr, nullptr, nullptr,
        res, nullptr, nullptr, nullptr, vpebuf, nullptr);
  }

  k_mm<4><<<dim3(128, 1), 512, 0, stream>>>(res, fc2T, 0, fc2b, nullptr,
      scbuf, nullptr, nullptr, nullptr, nullptr, nullptr, nullptr,
      nullptr, nullptr, nullptr, nullptr, nullptr, (float*)d_out);
}

// Round 12
// 486.442 us; speedup vs baseline: 1.9815x; 1.9815x over previous
//
#include <hip/hip_runtime.h>
#include <hip/hip_bf16.h>
#include <math.h>

typedef __attribute__((ext_vector_type(8))) short bf16x8;
typedef __attribute__((ext_vector_type(4))) float f32x4;
typedef __attribute__((ext_vector_type(4))) short s16x4;
typedef unsigned int u32;
typedef unsigned long long u64;

#define NBATCH 4
#define NPTS   4096
#define NTOT   (NBATCH*NPTS)     // 16384 points
#define NROWS  (NTOT*16)         // 262144 (point,neighbor) rows

__device__ __forceinline__ float bf2f(unsigned short h){
  unsigned int u = ((unsigned int)h) << 16;
  return __builtin_bit_cast(float, u);
}
__device__ __forceinline__ unsigned short f2bf(float f){
  unsigned int u = __builtin_bit_cast(unsigned int, f);
  u += 0x7FFFu + ((u >> 16) & 1u);   // RNE
  return (unsigned short)(u >> 16);
}
__device__ __forceinline__ unsigned short f2bfh(float f){   // HW cvt (RNE, pairs fuse to cvt_pk)
  return __bfloat16_as_ushort(__float2bfloat16(f));
}

#define MFMA(a,b,c) __builtin_amdgcn_mfma_f32_16x16x32_bf16((a),(b),(c),0,0,0)

typedef u32 __attribute__((address_space(1))) gas_u32;
typedef u32 __attribute__((address_space(3))) las_u32;
__device__ __forceinline__ void gl_lds16(const void* g, void* l){
  __builtin_amdgcn_global_load_lds((const gas_u32*)g, (las_u32*)l, 16, 0, 0);
}

// wave-internal LDS ordering fence (rule #18 pattern)
__device__ __forceinline__ void wfence(){
  asm volatile("s_waitcnt lgkmcnt(0)" ::: "memory");
  __builtin_amdgcn_sched_barrier(0);
}

// ---------------- prep: features -> bf16 ----------------
__global__ __launch_bounds__(256) void k_convert(const float* __restrict__ x,
                                                 unsigned short* __restrict__ xb, int n){
  int i = (blockIdx.x * 256 + threadIdx.x) * 4;
  if (i < n){
    float4 v = *(const float4*)(x + i);
    s16x4 o;
    o[0] = (short)f2bf(v.x); o[1] = (short)f2bf(v.y);
    o[2] = (short)f2bf(v.z); o[3] = (short)f2bf(v.w);
    *(s16x4*)(xb + i) = o;
  }
}

// ---------------- prep: xyz -> float4 (x,y,z,|p|^2) ----------------
__global__ __launch_bounds__(256) void k_xyzw(const float* __restrict__ xyz,
                                              float4* __restrict__ xyzw){
  int i = blockIdx.x * 256 + threadIdx.x;   // 16384
  float x = xyz[i*3], y = xyz[i*3+1], z = xyz[i*3+2];
  xyzw[i] = make_float4(x, y, z, x*x + y*y + z*z);
}

// ---------------- prep: transposed bf16 weight copies ----------------
__global__ __launch_bounds__(256) void k_prep_mats(
    const float* __restrict__ scw, const float* __restrict__ g2,
    const float* __restrict__ fc2, const float* __restrict__ W2,
    const float* __restrict__ scb,
    unsigned short* __restrict__ qkv2T, unsigned short* __restrict__ g2sT,
    unsigned short* __restrict__ fc2T, unsigned short* __restrict__ BposT,
    float* __restrict__ cvec){
  int c = blockIdx.x, d = threadIdx.x;
  qkv2T[(768+c)*256 + d] = f2bf(scw[d*256 + c]);             // sc^T
  g2sT[c*256 + d]        = f2bf(g2[d*256 + c] * 0.0625f);    // fold 1/sqrt(DM)=1/16
  fc2T[c*256 + d]        = f2bf(fc2[d*256 + c]);
  BposT[(256+c)*256 + d] = f2bf(W2[d*256 + c]);              // W2^T (pe)
  if (d == 0) cvec[768 + c] = scb[c];
}

// ---------------- prep stage 1: Wqg = wq@g1, Wkg = wk@g1, W2g1, c1 ----------------
__global__ __launch_bounds__(256) void k_prep_gemm(
    const float* __restrict__ wq, const float* __restrict__ wk,
    const float* __restrict__ g1, const float* __restrict__ W2,
    const float* __restrict__ b2d, const float* __restrict__ gb1,
    unsigned short* __restrict__ tmpWq, unsigned short* __restrict__ tmpWk,
    unsigned short* __restrict__ BposT, float* __restrict__ c1){
  int c = threadIdx.x, bid = blockIdx.x;
  if (bid < 256){
    int d = bid; float acc = 0.f;
    for (int e=0;e<256;e++) acc += wq[d*256+e]*g1[e*256+c];
    tmpWq[c*256 + d] = f2bf(acc);
  } else if (bid < 512){
    int d = bid-256; float acc = 0.f;
    for (int e=0;e<256;e++) acc += wk[d*256+e]*g1[e*256+c];
    tmpWk[c*256 + d] = f2bf(acc);
  } else if (bid < 768){
    int d = bid-512; float acc = 0.f;
    for (int e=0;e<256;e++) acc += W2[d*256+e]*g1[e*256+c];
    BposT[c*256 + d] = f2bf(acc);
  } else {
    float acc = 0.f;
    for (int e=0;e<256;e++) acc += b2d[e]*g1[e*256+c];
    c1[c] = acc + gb1[c];
  }
}

// ---------------- prep stage 2: fold fc1 into QKV ----------------
__global__ __launch_bounds__(256) void k_prep_gemm2(
    const float* __restrict__ fc1w, const float* __restrict__ fc1b,
    const float* __restrict__ wv,
    const unsigned short* __restrict__ tmpWq, const unsigned short* __restrict__ tmpWk,
    unsigned short* __restrict__ qkv2T, float* __restrict__ cvec){
  int c = threadIdx.x, bid = blockIdx.x;
  if (bid < 256){
    int d = bid; float acc = 0.f;
    for (int e=0;e<256;e++) acc += fc1w[d*256+e]*bf2f(tmpWq[c*256+e]);
    qkv2T[c*256 + d] = f2bf(acc);
  } else if (bid < 512){
    int d = bid-256; float acc = 0.f;
    for (int e=0;e<256;e++) acc += fc1w[d*256+e]*bf2f(tmpWk[c*256+e]);
    qkv2T[(256+c)*256 + d] = f2bf(acc);
  } else if (bid < 768){
    int d = bid-512; float acc = 0.f;
    for (int e=0;e<256;e++) acc += fc1w[d*256+e]*wv[e*256+c];
    qkv2T[(512+c)*256 + d] = f2bf(acc);
  } else {
    float aq=0.f, ak=0.f, av=0.f;
    for (int e=0;e<256;e++){
      float fb = fc1b[e];
      aq += fb*bf2f(tmpWq[c*256+e]);
      ak += fb*bf2f(tmpWk[c*256+e]);
      av += fb*wv[e*256+c];
    }
    cvec[c] = aq; cvec[256+c] = ak; cvec[512+c] = av;
  }
}

// ======== kNN via exact radix rank-select (r7/r10 structure: VGPR 36, occ 67%) ========
__device__ __forceinline__ u32 fmap(float d){
  u32 u = __builtin_bit_cast(u32, d);
  return ((int)u < 0) ? ~u : (u | 0x80000000u);
}

__device__ __forceinline__ void find_thresh(const int* hist, int lane, int need,
                                            int* e_out, int* c_out){
  int h0 = hist[lane*4], h1 = hist[lane*4+1], h2 = hist[lane*4+2], h3 = hist[lane*4+3];
  int ps = h0 + h1 + h2 + h3;
  int incl = ps;
  #pragma unroll
  for (int d = 1; d < 64; d <<= 1){
    int tv = __shfl_up(incl, d, 64);
    if (lane >= d) incl += tv;
  }
  int excl = incl - ps;
  int b0 = excl, b1 = excl + h0, b2 = b1 + h1, b3 = b2 + h2;
  bool f0 = (b0 < need) && (b0 + h0 >= need);
  bool f1 = (b1 < need) && (b1 + h1 >= need);
  bool f2 = (b2 < need) && (b2 + h2 >= need);
  bool f3 = (b3 < need) && (b3 + h3 >= need);
  int e_loc = f0 ? lane*4 : f1 ? lane*4+1 : f2 ? lane*4+2 : lane*4+3;
  int c_loc = f0 ? b0 : f1 ? b1 : f2 ? b2 : b3;
  u64 mk = __ballot(f0 | f1 | f2 | f3);
  int wl = __ffsll(mk) - 1;
  *e_out = __shfl(e_loc, wl, 64);
  *c_out = __shfl(c_loc, wl, 64);
}

__device__ __forceinline__ void find_thresh4(const int* hA, int lane, int need,
                                             int* e_out, int* c_out){
  int h[4];
  #pragma unroll
  for (int j=0;j<4;j++){
    int bin = lane*4+j;
    h[j] = hA[bin]
         + hA[256 + ((bin+8)&255)]
         + hA[512 + ((bin+16)&255)]
         + hA[768 + ((bin+24)&255)];
  }
  int ps = h[0] + h[1] + h[2] + h[3];
  int incl = ps;
  #pragma unroll
  for (int d = 1; d < 64; d <<= 1){
    int tv = __shfl_up(incl, d, 64);
    if (lane >= d) incl += tv;
  }
  int excl = incl - ps;
  int b0 = excl, b1 = excl + h[0], b2 = b1 + h[1], b3 = b2 + h[2];
  bool f0 = (b0 < need) && (b0 + h[0] >= need);
  bool f1 = (b1 < need) && (b1 + h[1] >= need);
  bool f2 = (b2 < need) && (b2 + h[2] >= need);
  bool f3 = (b3 < need) && (b3 + h[3] >= need);
  int e_loc = f0 ? lane*4 : f1 ? lane*4+1 : f2 ? lane*4+2 : lane*4+3;
  int c_loc = f0 ? b0 : f1 ? b1 : f2 ? b2 : b3;
  u64 mk = __ballot(f0 | f1 | f2 | f3);
  int wl = __ffsll(mk) - 1;
  *e_out = __shfl(e_loc, wl, 64);
  *c_out = __shfl(c_loc, wl, 64);
}

__global__ __launch_bounds__(256) void k_knn(const float4* __restrict__ xyzw,
                                             int* __restrict__ gidxbuf,
                                             float4* __restrict__ relbuf){
  __shared__ int histA[4][1024];    // 4 waves x 4 rotated copies x 256 bins
  __shared__ int histB[4][256];
  __shared__ u32 lstU[4][64];
  __shared__ int lstM[4][64];

  int t = threadIdx.x, lane = t & 63, wv = t >> 6;
  int widx = blockIdx.x * 4 + wv;          // 0..16383
  int b = widx >> 12, n = widx & 4095;
  const float4* xb = xyzw + (size_t)b * NPTS;
  float4 P = xb[n];
  float x2n = P.w;
  int* hA = histA[wv]; int* hB = histB[wv];

  #pragma unroll
  for (int j = 0; j < 16; j++) hA[lane*16+j] = 0;
  #pragma unroll
  for (int j = 0; j < 4; j++)  hB[lane*4+j] = 0;
  wfence();

  int cp = lane >> 4;                      // sub-copy 0..3 (16 lanes each)
  int cpoff = cp*256, cprot = cp*8;

  // pass 1: coarse histogram (top 8 bits), 2-way unrolled, rotated copies
  for (int it = 0; it < 64; it += 2){
    float4 Q0 = xb[it*64 + lane];
    float4 Q1 = xb[it*64 + 64 + lane];
    float d0 = x2n + Q0.w - 2.0f*(P.x*Q0.x + P.y*Q0.y + P.z*Q0.z);
    float d1 = x2n + Q1.w - 2.0f*(P.x*Q1.x + P.y*Q1.y + P.z*Q1.z);
    int b0 = (int)(fmap(d0) >> 24), b1 = (int)(fmap(d1) >> 24);
    atomicAdd(&hA[cpoff + ((b0 + cprot)&255)], 1);
    atomicAdd(&hA[cpoff + ((b1 + cprot)&255)], 1);
  }
  wfence();
  int e1, c0;
  find_thresh4(hA, lane, 16, &e1, &c0);

  // pass 2: refine within bin e1 (next 8 bits) — few active lanes, single copy
  for (int it = 0; it < 64; it++){
    float4 Q = xb[it*64 + lane];
    u32 u = fmap(x2n + Q.w - 2.0f*(P.x*Q.x + P.y*Q.y + P.z*Q.z));
    if ((int)(u >> 24) == e1) atomicAdd(&hB[(u >> 16) & 0xFF], 1);
  }
  wfence();
  int m1, cc;
  find_thresh(hB, lane, 16 - c0, &m1, &cc);
  int c1 = c0 + cc;                        // definite members, < 16
  u32 T16 = ((u32)e1 << 8) | (u32)m1;

  // pass 3: emit definite members; stash boundary sub-bin members
  int base = 0, Lc = 0;
  size_t orow = (size_t)widx * 16;
  for (int it = 0; it < 64; it++){
    int m = it*64 + lane;
    float4 Q = xb[m];
    u32 u = fmap(x2n + Q.w - 2.0f*(P.x*Q.x + P.y*Q.y + P.z*Q.z));
    u32 u16_ = u >> 16;
    bool def = u16_ < T16;
    bool bnd = u16_ == T16;
    u64 mkd = __ballot(def);
    if (def){
      int slot = base + __popcll(mkd & ((1ULL << lane) - 1ULL));
      gidxbuf[orow + slot] = b*NPTS + m;
      relbuf[orow + slot]  = make_float4(P.x - Q.x, P.y - Q.y, P.z - Q.z, 0.f);
    }
    base += __popcll(mkd);
    u64 mkb = __ballot(bnd);
    if (bnd){
      int sl = Lc + __popcll(mkb & ((1ULL << lane) - 1ULL));
      if (sl < 64){ lstU[wv][sl] = u; lstM[wv][sl] = m; }
    }
    Lc += __popcll(mkb);
  }
  wfence();
  if (Lc > 64) Lc = 64;

  // pop the remaining 16-c1 smallest (u, idx) lexicographically (== top_k tie-break)
  int r2 = 16 - c1;
  u32 lu = (lane < Lc) ? lstU[wv][lane] : 0xFFFFFFFFu;
  int lm = (lane < Lc) ? lstM[wv][lane] : 0x7FFFFFFF;
  bool popped = false;
  for (int r = 0; r < r2; r++){
    u32 ku = popped ? 0xFFFFFFFFu : lu;
    int km = popped ? 0x7FFFFFFF : lm;
    #pragma unroll
    for (int off = 32; off >= 1; off >>= 1){
      u32 ou = __shfl_xor(ku, off, 64);
      int om = __shfl_xor(km, off, 64);
      if (ou < ku || (ou == ku && om < km)){ ku = ou; km = om; }
    }
    bool mine = !popped && (lane < Lc) && (lu == ku) && (lm == km);
    u64 mk = __ballot(mine);
    int wl = __ffsll(mk) - 1;
    if (lane == wl){
      popped = true;
      float4 Q = xb[km];
      gidxbuf[orow + c1 + r] = b*NPTS + km;
      relbuf[orow + c1 + r]  = make_float4(P.x - Q.x, P.y - Q.y, P.z - Q.z, 0.f);
    }
  }
}

// ============ unified GEMM: 512 thr (8 waves, 2x4), BM=128, BN=256, BK=32 ============
// MODE 0: QKV  A=Xb  BT=qkv2T  grid.y=4 (one 256-col buffer per y): qg|kg|v|sc (+cvec)
// MODE 2: G2   A=on-the-fly H  BT=BposT grid.y=2: y0 -> a1, y1 -> vpe
// MODE 3: G3   A=a1  BT=g2sT   grid.y=1: softmax+combine(vpe) -> res
// MODE 4: FIN  A=res BT=fc2T   grid.y=1: fp32 out (+fc2b+sc)
template<int MODE>
__global__ __launch_bounds__(512) void k_mm(
    const unsigned short* __restrict__ A, const unsigned short* __restrict__ BT,
    int rowbase,
    const float* __restrict__ bias, const float* __restrict__ b2v,
    const unsigned short* __restrict__ qg, const unsigned short* __restrict__ kg,
    const unsigned short* __restrict__ vb,
    const float4* __restrict__ relbuf, const int* __restrict__ gidxbuf,
    const float* __restrict__ W1, const float* __restrict__ b1d,
    unsigned short* __restrict__ o0, unsigned short* __restrict__ o1,
    unsigned short* __restrict__ o2, unsigned short* __restrict__ o3,
    const unsigned short* __restrict__ vper,
    float* __restrict__ fout){
  __shared__ unsigned short As[4096];   // 128 x 32
  __shared__ unsigned short Bs[8192];   // 256 x 32
  __shared__ float4 W1s4[256];          // (w1x,w1y,w1z,b1) per column (MODE 2)
  __shared__ float4 relS[128];
  __shared__ int    gidxS[128];
  __shared__ float  biasS[256];

  int t = threadIdx.x;
  int lane = t & 63, w = t >> 6;
  int wm = w >> 2, wn = w & 3;          // 2 x 4 wave grid
  int lrow = lane & 15, lkg = lane >> 4;
  int bx = blockIdx.x;
  if constexpr (MODE == 2){
    int gx = gridDim.x;
    bx = (bx & 7) * (gx >> 3) + (bx >> 3);   // XCD-aware swizzle (gridDim.x % 8 == 0)
  }
  int m0 = bx * 128, n0 = blockIdx.y * 256;

  float4 rl0 = make_float4(0.f,0.f,0.f,0.f);
  if constexpr (MODE == 2){
    if (t < 128){
      relS[t]  = relbuf[(size_t)rowbase + m0 + t];
      gidxS[t] = gidxbuf[(size_t)rowbase + m0 + t];
    }
    if (t < 256){
      biasS[t] = (blockIdx.y == 0) ? bias[t] : b2v[t];
      W1s4[t] = make_float4(W1[t], W1[256+t], W1[512+t], b1d[t]);
    }
    __syncthreads();
    rl0 = relS[t >> 2];                 // hoisted: loop-invariant across k0
  }
  if constexpr (MODE == 0){
    if (t < 256) biasS[t] = bias[n0 + t];   // K-loop barrier orders this before use
  }

  int sr = t >> 2, sc = (t & 3) * 8;               // staging: row 0..127, col(8 bf16=16B)
  unsigned short* lA  = As + (w << 9);             // wave-uniform LDS bases (1KB/wave)
  unsigned short* lB  = Bs + (w << 9);
  unsigned short* lB2 = Bs + 4096 + (w << 9);
  const unsigned short* gB  = BT + (size_t)(n0 + sr)*256 + sc;
  const unsigned short* gB2 = BT + (size_t)(n0 + 128 + sr)*256 + sc;

  f32x4 acc[4][4] = {};
  for (int k0 = 0; k0 < 256; k0 += 32){
    if constexpr (MODE == 2){
      // compute H tile rows [m0,m0+128) cols [k0,k0+32) on the fly
      int r = t >> 2, h = (t & 3) << 3;
      bf16x8 h0;
      #pragma unroll
      for (int j = 0; j < 8; j++){
        int c = k0 + h + j;
        float4 wa = W1s4[c];
        float x0 = rl0.x*wa.x + rl0.y*wa.y + rl0.z*wa.z + wa.w;
        h0[j] = (short)f2bfh(fmaxf(x0, 0.f));
      }
      *(bf16x8*)&As[r*32 + h] = h0;
    } else {
      const unsigned short* gA = A + (size_t)(m0 + sr)*256 + k0 + sc;
      gl_lds16(gA, lA);
    }
    gl_lds16(gB  + k0, lB);
    gl_lds16(gB2 + k0, lB2);
    __syncthreads();
    bf16x8 af[4], bfr[4];
    #pragma unroll
    for (int fi = 0; fi < 4; fi++)
      af[fi] = *(const bf16x8*)&As[(wm*64 + fi*16 + lrow)*32 + lkg*8];
    #pragma unroll
    for (int nf = 0; nf < 4; nf++)
      bfr[nf] = *(const bf16x8*)&Bs[(wn*64 + nf*16 + lrow)*32 + lkg*8];
    #pragma unroll
    for (int fi = 0; fi < 4; fi++)
      #pragma unroll
      for (int nf = 0; nf < 4; nf++)
        acc[fi][nf] = MFMA(af[fi], bfr[nf], acc[fi][nf]);
    __syncthreads();
  }

  if constexpr (MODE == 0){
    unsigned short* outp = (blockIdx.y==0)?o0:(blockIdx.y==1)?o1:(blockIdx.y==2)?o2:o3;
    #pragma unroll
    for (int fi=0; fi<4; fi++)
      #pragma unroll
      for (int nf=0; nf<4; nf++)
        #pragma unroll
        for (int r=0;r<4;r++){
          int row = m0 + wm*64 + fi*16 + lkg*4 + r;
          int col = wn*64 + nf*16 + lrow;            // 0..255
          outp[(size_t)row*256 + col] = f2bf(acc[fi][nf][r] + biasS[col]);
        }
  } else if constexpr (MODE == 2){
    const bool is_a1 = (blockIdx.y == 0);
    #pragma unroll
    for (int fi=0; fi<4; fi++){
      int g = (rowbase + m0 + wm*64 + fi*16) >> 4;   // point id (16 rows = 1 point)
      #pragma unroll
      for (int nf=0; nf<4; nf++){
        int colg = wn*64 + nf*16 + lrow;             // 0..255
        if (is_a1){
          float qv = bf2f(qg[(size_t)g*256 + colg]) + biasS[colg];   // biasS = c1
          #pragma unroll
          for (int r=0;r<4;r++){
            int rl_ = wm*64 + fi*16 + lkg*4 + r;
            int gi = gidxS[rl_];
            float a1 = acc[fi][nf][r] + qv - bf2f(kg[(size_t)gi*256 + colg]);
            o0[(size_t)(m0 + rl_)*256 + colg] = f2bfh(fmaxf(a1, 0.f));
          }
        } else {
          float bb = biasS[colg];                    // biasS = b2
          #pragma unroll
          for (int r=0;r<4;r++){
            int rl_ = wm*64 + fi*16 + lkg*4 + r;
            int gi = gidxS[rl_];
            float vpe = acc[fi][nf][r] + bb + bf2f(vb[(size_t)gi*256 + colg]);
            o1[(size_t)(m0 + rl_)*256 + colg] = f2bfh(vpe);
          }
        }
      }
    }
  } else if constexpr (MODE == 3){
    #pragma unroll
    for (int fi=0; fi<4; fi++){
      int g = (rowbase + m0 + wm*64 + fi*16) >> 4;
      #pragma unroll
      for (int nf=0; nf<4; nf++){
        int colg = wn*64 + nf*16 + lrow;             // 0..255
        float s[4], e[4];
        #pragma unroll
        for (int r=0;r<4;r++) s[r] = acc[fi][nf][r] + bias[colg]*0.0625f;  // bias = gb2
        float mx = fmaxf(fmaxf(s[0],s[1]), fmaxf(s[2],s[3]));
        mx = fmaxf(mx, __shfl_xor(mx,16,64));
        mx = fmaxf(mx, __shfl_xor(mx,32,64));
        float sm = 0.f;
        #pragma unroll
        for (int r=0;r<4;r++){ e[r] = __expf(s[r]-mx); sm += e[r]; }
        sm += __shfl_xor(sm,16,64);
        sm += __shfl_xor(sm,32,64);
        float rs = 1.f/sm, tsum = 0.f;
        #pragma unroll
        for (int r=0;r<4;r++){
          int rl_ = wm*64 + fi*16 + lkg*4 + r;
          tsum += (e[r]*rs) * bf2f(vper[(size_t)(m0 + rl_)*256 + colg]);
        }
        tsum += __shfl_xor(tsum,16,64);
        tsum += __shfl_xor(tsum,32,64);
        if (lkg == 0) o0[(size_t)g*256 + colg] = f2bf(tsum);
      }
    }
  } else {   // FIN
    #pragma unroll
    for (int fi=0; fi<4; fi++)
      #pragma unroll
      for (int nf=0; nf<4; nf++)
        #pragma unroll
        for (int r=0;r<4;r++){
          int row = m0 + wm*64 + fi*16 + lkg*4 + r;
          int col = wn*64 + nf*16 + lrow;
          fout[(size_t)row*256 + col] = acc[fi][nf][r] + bias[col]
                                      + bf2f(qg[(size_t)row*256 + col]);  // qg slot = scbuf
        }
  }
}

// ---------------- host ----------------
extern "C" void kernel_launch(void* const* d_in, const int* in_sizes, int n_in,
                              void* d_out, int out_size, void* d_ws, size_t ws_size,
                              hipStream_t stream){
  (void)in_sizes; (void)n_in; (void)out_size;
  const float* xyz  = (const float*)d_in[0];
  const float* feat = (const float*)d_in[1];
  const float* W1   = (const float*)d_in[2];
  const float* b1d  = (const float*)d_in[3];
  const float* W2   = (const float*)d_in[4];
  const float* b2d  = (const float*)d_in[5];
  const float* fc1w = (const float*)d_in[6];
  const float* fc1b = (const float*)d_in[7];
  const float* wq   = (const float*)d_in[8];
  const float* wk   = (const float*)d_in[9];
  const float* wv   = (const float*)d_in[10];
  const float* g1   = (const float*)d_in[11];
  const float* gb1  = (const float*)d_in[12];
  const float* g2   = (const float*)d_in[13];
  const float* gb2  = (const float*)d_in[14];
  const float* fc2w = (const float*)d_in[15];
  const float* fc2b = (const float*)d_in[16];
  const float* scw  = (const float*)d_in[17];
  const float* scb  = (const float*)d_in[18];

  char* ws = (char*)d_ws;
  size_t off = 0;
  auto alloc = [&](size_t bytes)->void*{ void* p = ws + off; off += (bytes + 255) & ~(size_t)255; return p; };
  unsigned short* Xb     = (unsigned short*)alloc((size_t)NTOT*256*2);  // reused as res
  unsigned short* qgb    = (unsigned short*)alloc((size_t)NTOT*256*2);
  unsigned short* kgb    = (unsigned short*)alloc((size_t)NTOT*256*2);
  unsigned short* vbb    = (unsigned short*)alloc((size_t)NTOT*256*2);
  unsigned short* scbuf  = (unsigned short*)alloc((size_t)NTOT*256*2);
  int*            gidxbuf= (int*)alloc((size_t)NROWS*4);
  float4*         relbuf = (float4*)alloc((size_t)NROWS*16);
  float4*         xyzw   = (float4*)alloc((size_t)NTOT*16);
  unsigned short* qkv2T  = (unsigned short*)alloc(1024*256*2);
  unsigned short* tmpWq  = (unsigned short*)alloc(256*256*2);
  unsigned short* tmpWk  = (unsigned short*)alloc(256*256*2);
  unsigned short* BposT  = (unsigned short*)alloc(512*256*2);
  unsigned short* g2sT   = (unsigned short*)alloc(256*256*2);
  unsigned short* fc2T   = (unsigned short*)alloc(256*256*2);
  float*          c1     = (float*)alloc(256*4);
  float*          cvec   = (float*)alloc(1024*4);
  unsigned short* res    = Xb;

  // adaptive chunk: a1 + vpe cost CR*1024 bytes (single chunk if ws allows)
  int CR = NROWS;
  while (CR > 16384 && off + (size_t)CR*1024 > ws_size) CR >>= 1;
  unsigned short* a1buf  = (unsigned short*)alloc((size_t)CR*256*2);
  unsigned short* vpebuf = (unsigned short*)alloc((size_t)CR*256*2);

  k_convert<<<4096, 256, 0, stream>>>(feat, Xb, NTOT*256);
  k_xyzw<<<64, 256, 0, stream>>>(xyz, xyzw);
  k_prep_mats<<<256, 256, 0, stream>>>(scw, g2, fc2w, W2, scb, qkv2T, g2sT, fc2T, BposT, cvec);
  k_prep_gemm<<<769, 256, 0, stream>>>(wq, wk, g1, W2, b2d, gb1, tmpWq, tmpWk, BposT, c1);
  k_prep_gemm2<<<769, 256, 0, stream>>>(fc1w, fc1b, wv, tmpWq, tmpWk, qkv2T, cvec);
  k_knn<<<4096, 256, 0, stream>>>(xyzw, gidxbuf, relbuf);

  k_mm<0><<<dim3(128, 4), 512, 0, stream>>>(Xb, qkv2T, 0, cvec, nullptr,
      nullptr, nullptr, nullptr, nullptr, nullptr, nullptr, nullptr,
      qgb, kgb, vbb, scbuf, nullptr, nullptr);

  for (int c0 = 0; c0 < NROWS; c0 += CR){
    k_mm<2><<<dim3(CR/128, 2), 512, 0, stream>>>(nullptr, BposT, c0, c1, b2d,
        qgb, kgb, vbb, relbuf, gidxbuf, W1, b1d,
        a1buf, vpebuf, nullptr, nullptr, nullptr, nullptr);
    k_mm<3><<<dim3(CR/128, 1), 512, 0, stream>>>(a1buf, g2sT, c0, gb2, nullptr,
        nullptr, nullptr, nullptr, nullptr, nullptr, nullptr, nullptr,
        res, nullptr, nullptr, nullptr, vpebuf, nullptr);
  }

  k_mm<4><<<dim3(128, 1), 512, 0, stream>>>(res, fc2T, 0, fc2b, nullptr,
      scbuf, nullptr, nullptr, nullptr, nullptr, nullptr, nullptr,
      nullptr, nullptr, nullptr, nullptr, nullptr, (float*)d_out);
}

// Round 13
// 483.663 us; speedup vs baseline: 1.9929x; 1.0057x over previous
//
#include <hip/hip_runtime.h>
#include <hip/hip_bf16.h>
#include <math.h>

typedef __attribute__((ext_vector_type(8))) short bf16x8;
typedef __attribute__((ext_vector_type(4))) float f32x4;
typedef __attribute__((ext_vector_type(4))) short s16x4;
typedef unsigned int u32;
typedef unsigned long long u64;

#define NBATCH 4
#define NPTS   4096
#define NTOT   (NBATCH*NPTS)     // 16384 points
#define NROWS  (NTOT*16)         // 262144 (point,neighbor) rows

__device__ __forceinline__ float bf2f(unsigned short h){
  unsigned int u = ((unsigned int)h) << 16;
  return __builtin_bit_cast(float, u);
}
__device__ __forceinline__ unsigned short f2bf(float f){
  unsigned int u = __builtin_bit_cast(unsigned int, f);
  u += 0x7FFFu + ((u >> 16) & 1u);   // RNE
  return (unsigned short)(u >> 16);
}
__device__ __forceinline__ unsigned short f2bfh(float f){   // HW cvt (RNE, pairs fuse to cvt_pk)
  return __bfloat16_as_ushort(__float2bfloat16(f));
}

#define MFMA(a,b,c) __builtin_amdgcn_mfma_f32_16x16x32_bf16((a),(b),(c),0,0,0)

typedef u32 __attribute__((address_space(1))) gas_u32;
typedef u32 __attribute__((address_space(3))) las_u32;
__device__ __forceinline__ void gl_lds16(const void* g, void* l){
  __builtin_amdgcn_global_load_lds((const gas_u32*)g, (las_u32*)l, 16, 0, 0);
}

// wave-internal LDS ordering fence (rule #18 pattern)
__device__ __forceinline__ void wfence(){
  asm volatile("s_waitcnt lgkmcnt(0)" ::: "memory");
  __builtin_amdgcn_sched_barrier(0);
}

// ---------------- prep: features -> bf16 ----------------
__global__ __launch_bounds__(256) void k_convert(const float* __restrict__ x,
                                                 unsigned short* __restrict__ xb, int n){
  int i = (blockIdx.x * 256 + threadIdx.x) * 4;
  if (i < n){
    float4 v = *(const float4*)(x + i);
    s16x4 o;
    o[0] = (short)f2bf(v.x); o[1] = (short)f2bf(v.y);
    o[2] = (short)f2bf(v.z); o[3] = (short)f2bf(v.w);
    *(s16x4*)(xb + i) = o;
  }
}

// ---------------- prep: xyz -> float4 (x,y,z,|p|^2) ----------------
__global__ __launch_bounds__(256) void k_xyzw(const float* __restrict__ xyz,
                                              float4* __restrict__ xyzw){
  int i = blockIdx.x * 256 + threadIdx.x;   // 16384
  float x = xyz[i*3], y = xyz[i*3+1], z = xyz[i*3+2];
  xyzw[i] = make_float4(x, y, z, x*x + y*y + z*z);
}

// ---------------- prep: transposed bf16 weight copies ----------------
__global__ __launch_bounds__(256) void k_prep_mats(
    const float* __restrict__ scw, const float* __restrict__ g2,
    const float* __restrict__ fc2, const float* __restrict__ W2,
    const float* __restrict__ scb,
    unsigned short* __restrict__ qkv2T, unsigned short* __restrict__ g2sT,
    unsigned short* __restrict__ fc2T, unsigned short* __restrict__ BposT,
    float* __restrict__ cvec){
  int c = blockIdx.x, d = threadIdx.x;
  qkv2T[(768+c)*256 + d] = f2bf(scw[d*256 + c]);             // sc^T
  g2sT[c*256 + d]        = f2bf(g2[d*256 + c] * 0.0625f);    // fold 1/sqrt(DM)=1/16
  fc2T[c*256 + d]        = f2bf(fc2[d*256 + c]);
  BposT[(256+c)*256 + d] = f2bf(W2[d*256 + c]);              // W2^T (pe)
  if (d == 0) cvec[768 + c] = scb[c];
}

// ---------------- prep stage 1: Wqg = wq@g1, Wkg = wk@g1, W2g1, c1 ----------------
__global__ __launch_bounds__(256) void k_prep_gemm(
    const float* __restrict__ wq, const float* __restrict__ wk,
    const float* __restrict__ g1, const float* __restrict__ W2,
    const float* __restrict__ b2d, const float* __restrict__ gb1,
    unsigned short* __restrict__ tmpWq, unsigned short* __restrict__ tmpWk,
    unsigned short* __restrict__ BposT, float* __restrict__ c1){
  int c = threadIdx.x, bid = blockIdx.x;
  if (bid < 256){
    int d = bid; float acc = 0.f;
    for (int e=0;e<256;e++) acc += wq[d*256+e]*g1[e*256+c];
    tmpWq[c*256 + d] = f2bf(acc);
  } else if (bid < 512){
    int d = bid-256; float acc = 0.f;
    for (int e=0;e<256;e++) acc += wk[d*256+e]*g1[e*256+c];
    tmpWk[c*256 + d] = f2bf(acc);
  } else if (bid < 768){
    int d = bid-512; float acc = 0.f;
    for (int e=0;e<256;e++) acc += W2[d*256+e]*g1[e*256+c];
    BposT[c*256 + d] = f2bf(acc);
  } else {
    float acc = 0.f;
    for (int e=0;e<256;e++) acc += b2d[e]*g1[e*256+c];
    c1[c] = acc + gb1[c];
  }
}

// ---------------- prep stage 2: fold fc1 into QKV ----------------
__global__ __launch_bounds__(256) void k_prep_gemm2(
    const float* __restrict__ fc1w, const float* __restrict__ fc1b,
    const float* __restrict__ wv,
    const unsigned short* __restrict__ tmpWq, const unsigned short* __restrict__ tmpWk,
    unsigned short* __restrict__ qkv2T, float* __restrict__ cvec){
  int c = threadIdx.x, bid = blockIdx.x;
  if (bid < 256){
    int d = bid; float acc = 0.f;
    for (int e=0;e<256;e++) acc += fc1w[d*256+e]*bf2f(tmpWq[c*256+e]);
    qkv2T[c*256 + d] = f2bf(acc);
  } else if (bid < 512){
    int d = bid-256; float acc = 0.f;
    for (int e=0;e<256;e++) acc += fc1w[d*256+e]*bf2f(tmpWk[c*256+e]);
    qkv2T[(256+c)*256 + d] = f2bf(acc);
  } else if (bid < 768){
    int d = bid-512; float acc = 0.f;
    for (int e=0;e<256;e++) acc += fc1w[d*256+e]*wv[e*256+c];
    qkv2T[(512+c)*256 + d] = f2bf(acc);
  } else {
    float aq=0.f, ak=0.f, av=0.f;
    for (int e=0;e<256;e++){
      float fb = fc1b[e];
      aq += fb*bf2f(tmpWq[c*256+e]);
      ak += fb*bf2f(tmpWk[c*256+e]);
      av += fb*wv[e*256+c];
    }
    cvec[c] = aq; cvec[256+c] = ak; cvec[512+c] = av;
  }
}

// ======== kNN: radix rank-select, 2 full scans (pass2 merged into pass3) ========
__device__ __forceinline__ u32 fmap(float d){
  u32 u = __builtin_bit_cast(u32, d);
  return ((int)u < 0) ? ~u : (u | 0x80000000u);
}

__device__ __forceinline__ void find_thresh(const int* hist, int lane, int need,
                                            int* e_out, int* c_out){
  int h0 = hist[lane*4], h1 = hist[lane*4+1], h2 = hist[lane*4+2], h3 = hist[lane*4+3];
  int ps = h0 + h1 + h2 + h3;
  int incl = ps;
  #pragma unroll
  for (int d = 1; d < 64; d <<= 1){
    int tv = __shfl_up(incl, d, 64);
    if (lane >= d) incl += tv;
  }
  int excl = incl - ps;
  int b0 = excl, b1 = excl + h0, b2 = b1 + h1, b3 = b2 + h2;
  bool f0 = (b0 < need) && (b0 + h0 >= need);
  bool f1 = (b1 < need) && (b1 + h1 >= need);
  bool f2 = (b2 < need) && (b2 + h2 >= need);
  bool f3 = (b3 < need) && (b3 + h3 >= need);
  int e_loc = f0 ? lane*4 : f1 ? lane*4+1 : f2 ? lane*4+2 : lane*4+3;
  int c_loc = f0 ? b0 : f1 ? b1 : f2 ? b2 : b3;
  u64 mk = __ballot(f0 | f1 | f2 | f3);
  int wl = __ffsll(mk) - 1;
  *e_out = __shfl(e_loc, wl, 64);
  *c_out = __shfl(c_loc, wl, 64);
}

__device__ __forceinline__ void find_thresh4(const int* hA, int lane, int need,
                                             int* e_out, int* c_out){
  int h[4];
  #pragma unroll
  for (int j=0;j<4;j++){
    int bin = lane*4+j;
    h[j] = hA[bin]
         + hA[256 + ((bin+8)&255)]
         + hA[512 + ((bin+16)&255)]
         + hA[768 + ((bin+24)&255)];
  }
  int ps = h[0] + h[1] + h[2] + h[3];
  int incl = ps;
  #pragma unroll
  for (int d = 1; d < 64; d <<= 1){
    int tv = __shfl_up(incl, d, 64);
    if (lane >= d) incl += tv;
  }
  int excl = incl - ps;
  int b0 = excl, b1 = excl + h[0], b2 = b1 + h[1], b3 = b2 + h[2];
  bool f0 = (b0 < need) && (b0 + h[0] >= need);
  bool f1 = (b1 < need) && (b1 + h[1] >= need);
  bool f2 = (b2 < need) && (b2 + h[2] >= need);
  bool f3 = (b3 < need) && (b3 + h[3] >= need);
  int e_loc = f0 ? lane*4 : f1 ? lane*4+1 : f2 ? lane*4+2 : lane*4+3;
  int c_loc = f0 ? b0 : f1 ? b1 : f2 ? b2 : b3;
  u64 mk = __ballot(f0 | f1 | f2 | f3);
  int wl = __ffsll(mk) - 1;
  *e_out = __shfl(e_loc, wl, 64);
  *c_out = __shfl(c_loc, wl, 64);
}

__global__ __launch_bounds__(256) void k_knn(const float4* __restrict__ xyzw,
                                             int* __restrict__ gidxbuf,
                                             float4* __restrict__ relbuf){
  __shared__ int histA[4][1024];    // 16KB: 4 waves x 4 rotated copies x 256 bins
  __shared__ int histB[4][256];     // 4KB  -> total 20KB -> 8 blocks/CU

  int t = threadIdx.x, lane = t & 63, wv = t >> 6;
  int widx = blockIdx.x * 4 + wv;          // 0..16383
  int b = widx >> 12, n = widx & 4095;
  const float4* xb = xyzw + (size_t)b * NPTS;
  float4 P = xb[n];
  float x2n = P.w;
  int* hA = histA[wv]; int* hB = histB[wv];

  #pragma unroll
  for (int j = 0; j < 16; j++) hA[lane*16+j] = 0;
  #pragma unroll
  for (int j = 0; j < 4; j++)  hB[lane*4+j] = 0;
  wfence();

  int cp = lane >> 4;                      // sub-copy 0..3 (16 lanes each)
  int cpoff = cp*256, cprot = cp*8;

  // pass 1: coarse histogram (top 8 bits), 2-way unrolled, rotated copies
  for (int it = 0; it < 64; it += 2){
    float4 Q0 = xb[it*64 + lane];
    float4 Q1 = xb[it*64 + 64 + lane];
    float d0 = x2n + Q0.w - 2.0f*(P.x*Q0.x + P.y*Q0.y + P.z*Q0.z);
    float d1 = x2n + Q1.w - 2.0f*(P.x*Q1.x + P.y*Q1.y + P.z*Q1.z);
    int b0 = (int)(fmap(d0) >> 24), b1 = (int)(fmap(d1) >> 24);
    atomicAdd(&hA[cpoff + ((b0 + cprot)&255)], 1);
    atomicAdd(&hA[cpoff + ((b1 + cprot)&255)], 1);
  }
  wfence();
  int e1, c0dummy;
  find_thresh4(hA, lane, 16, &e1, &c0dummy);
  wfence();                                 // histA reads done; region reused below

  // lists alias the dead histA region (per wave, 1024 ints available)
  u32* lstE_u = (u32*)&hA[0];               // boundary-bin entries, cap 128
  int* lstE_m = &hA[128];
  u32* lstT_u = (u32*)&hA[256];             // tie entries, cap 64
  int* lstT_m = &hA[320];

  // merged pass 2+3: ONE scan — emit hi<e1 defs, hist+stash hi==e1 bin
  int base = 0, Lc = 0;
  size_t orow = (size_t)widx * 16;
  for (int it = 0; it < 64; it++){
    int m = it*64 + lane;
    float4 Q = xb[m];
    u32 u = fmap(x2n + Q.w - 2.0f*(P.x*Q.x + P.y*Q.y + P.z*Q.z));
    int hi = (int)(u >> 24);
    bool def = hi < e1;
    bool bnd = hi == e1;
    u64 mkd = __ballot(def);
    if (def){
      int slot = base + __popcll(mkd & ((1ULL << lane) - 1ULL));
      gidxbuf[orow + slot] = b*NPTS + m;
      relbuf[orow + slot]  = make_float4(P.x - Q.x, P.y - Q.y, P.z - Q.z, 0.f);
    }
    base += __popcll(mkd);
    u64 mkb = __ballot(bnd);
    if (bnd){
      int sl = Lc + __popcll(mkb & ((1ULL << lane) - 1ULL));
      if (sl < 128){ lstE_u[sl] = u; lstE_m[sl] = m; }
      atomicAdd(&hB[(u >> 16) & 0xFF], 1);
    }
    Lc += __popcll(mkb);
  }
  wfence();
  int c0 = base;                            // count of hi<e1 (wave-uniform, <16)
  int m1, cc;
  find_thresh(hB, lane, 16 - c0, &m1, &cc);
  int c1 = c0 + cc;                         // definite members, < 16

  // stage 2: emit mid<m1 members; collect ties (mid==m1) into lstT
  int nt = 0;
  if (Lc <= 128){
    int eb = c0;
    for (int ch = 0; ch < 128; ch += 64){
      int idx = ch + lane;
      bool valid = idx < Lc;
      u32 u = valid ? lstE_u[idx] : 0xFFFFFFFFu;
      int mid = valid ? (int)((u >> 16) & 0xFF) : 999;
      bool lt = valid && (mid < m1);
      u64 mk = __ballot(lt);
      if (lt){
        int slot = eb + __popcll(mk & ((1ULL << lane) - 1ULL));
        int m = lstE_m[idx];
        float4 Q = xb[m];
        gidxbuf[orow + slot] = b*NPTS + m;
        relbuf[orow + slot]  = make_float4(P.x - Q.x, P.y - Q.y, P.z - Q.z, 0.f);
      }
      eb += __popcll(mk);
      bool tie = valid && (mid == m1);
      u64 mkt = __ballot(tie);
      if (tie){
        int sl = nt + __popcll(mkt & ((1ULL << lane) - 1ULL));
        if (sl < 64){ lstT_u[sl] = u; lstT_m[sl] = lstE_m[idx]; }
      }
      nt += __popcll(mkt);
      if (Lc <= 64) break;
    }
  } else {
    // fallback (rare): full rescan of the boundary bin — exactness preserved
    int eb = c0;
    for (int it = 0; it < 64; it++){
      int m = it*64 + lane;
      float4 Q = xb[m];
      u32 u = fmap(x2n + Q.w - 2.0f*(P.x*Q.x + P.y*Q.y + P.z*Q.z));
      bool inb = ((int)(u >> 24) == e1);
      int mid = inb ? (int)((u >> 16) & 0xFF) : 999;
      bool lt = inb && (mid < m1);
      u64 mk = __ballot(lt);
      if (lt){
        int slot = eb + __popcll(mk & ((1ULL << lane) - 1ULL));
        gidxbuf[orow + slot] = b*NPTS + m;
        relbuf[orow + slot]  = make_float4(P.x - Q.x, P.y - Q.y, P.z - Q.z, 0.f);
      }
      eb += __popcll(mk);
      bool tie = inb && (mid == m1);
      u64 mkt = __ballot(tie);
      if (tie){
        int sl = nt + __popcll(mkt & ((1ULL << lane) - 1ULL));
        if (sl < 64){ lstT_u[sl] = u; lstT_m[sl] = m; }
      }
      nt += __popcll(mkt);
    }
  }
  wfence();
  if (nt > 64) nt = 64;

  // pop the remaining 16-c1 smallest (u, idx) lexicographically (== top_k tie-break)
  int r2 = 16 - c1;
  u32 lu = (lane < nt) ? lstT_u[lane] : 0xFFFFFFFFu;
  int lm = (lane < nt) ? lstT_m[lane] : 0x7FFFFFFF;
  bool popped = false;
  for (int r = 0; r < r2; r++){
    u32 ku = popped ? 0xFFFFFFFFu : lu;
    int km = popped ? 0x7FFFFFFF : lm;
    #pragma unroll
    for (int off = 32; off >= 1; off >>= 1){
      u32 ou = __shfl_xor(ku, off, 64);
      int om = __shfl_xor(km, off, 64);
      if (ou < ku || (ou == ku && om < km)){ ku = ou; km = om; }
    }
    bool mine = !popped && (lane < nt) && (lu == ku) && (lm == km);
    u64 mk = __ballot(mine);
    int wl = __ffsll(mk) - 1;
    if (lane == wl){
      popped = true;
      float4 Q = xb[km];
      gidxbuf[orow + c1 + r] = b*NPTS + km;
      relbuf[orow + c1 + r]  = make_float4(P.x - Q.x, P.y - Q.y, P.z - Q.z, 0.f);
    }
  }
}

// ============ unified GEMM: 512 thr (8 waves, 2x4), BM=128, BN=256, BK=32 ============
// MODE 0: QKV  A=Xb  BT=qkv2T  grid.y=4 (one 256-col buffer per y): qg|kg|v|sc (+cvec)
// MODE 2: G2   A=on-the-fly H  BT=BposT grid.y=2: y0 -> a1, y1 -> vpe
// MODE 3: G3   A=a1  BT=g2sT   grid.y=1: softmax+combine(vpe) -> res
// MODE 4: FIN  A=res BT=fc2T   grid.y=1: fp32 out (+fc2b+sc)
template<int MODE>
__global__ __launch_bounds__(512) void k_mm(
    const unsigned short* __restrict__ A, const unsigned short* __restrict__ BT,
    int rowbase,
    const float* __restrict__ bias, const float* __restrict__ b2v,
    const unsigned short* __restrict__ qg, const unsigned short* __restrict__ kg,
    const unsigned short* __restrict__ vb,
    const float4* __restrict__ relbuf, const int* __restrict__ gidxbuf,
    const float* __restrict__ W1, const float* __restrict__ b1d,
    unsigned short* __restrict__ o0, unsigned short* __restrict__ o1,
    unsigned short* __restrict__ o2, unsigned short* __restrict__ o3,
    const unsigned short* __restrict__ vper,
    float* __restrict__ fout){
  __shared__ unsigned short As[4096];   // 128 x 32
  __shared__ unsigned short Bs[8192];   // 256 x 32
  __shared__ float4 W1s4[256];          // (w1x,w1y,w1z,b1) per column (MODE 2)
  __shared__ float4 relS[128];
  __shared__ int    gidxS[128];
  __shared__ float  biasS[256];

  int t = threadIdx.x;
  int lane = t & 63, w = t >> 6;
  int wm = w >> 2, wn = w & 3;          // 2 x 4 wave grid
  int lrow = lane & 15, lkg = lane >> 4;
  int bx = blockIdx.x;
  if constexpr (MODE == 2){
    int gx = gridDim.x;
    bx = (bx & 7) * (gx >> 3) + (bx >> 3);   // XCD-aware swizzle (gridDim.x % 8 == 0)
  }
  int m0 = bx * 128, n0 = blockIdx.y * 256;

  float4 rl0 = make_float4(0.f,0.f,0.f,0.f);
  if constexpr (MODE == 2){
    if (t < 128){
      relS[t]  = relbuf[(size_t)rowbase + m0 + t];
      gidxS[t] = gidxbuf[(size_t)rowbase + m0 + t];
    }
    if (t < 256){
      biasS[t] = (blockIdx.y == 0) ? bias[t] : b2v[t];
      W1s4[t] = make_float4(W1[t], W1[256+t], W1[512+t], b1d[t]);
    }
    __syncthreads();
    rl0 = relS[t >> 2];                 // hoisted: loop-invariant across k0
  }
  if constexpr (MODE == 0){
    if (t < 256) biasS[t] = bias[n0 + t];   // K-loop barrier orders this before use
  }

  int sr = t >> 2, sc = (t & 3) * 8;               // staging: row 0..127, col(8 bf16=16B)
  unsigned short* lA  = As + (w << 9);             // wave-uniform LDS bases (1KB/wave)
  unsigned short* lB  = Bs + (w << 9);
  unsigned short* lB2 = Bs + 4096 + (w << 9);
  const unsigned short* gB  = BT + (size_t)(n0 + sr)*256 + sc;
  const unsigned short* gB2 = BT + (size_t)(n0 + 128 + sr)*256 + sc;

  f32x4 acc[4][4] = {};
  for (int k0 = 0; k0 < 256; k0 += 32){
    if constexpr (MODE == 2){
      // compute H tile rows [m0,m0+128) cols [k0,k0+32) on the fly
      int r = t >> 2, h = (t & 3) << 3;
      bf16x8 h0;
      #pragma unroll
      for (int j = 0; j < 8; j++){
        int c = k0 + h + j;
        float4 wa = W1s4[c];
        float x0 = rl0.x*wa.x + rl0.y*wa.y + rl0.z*wa.z + wa.w;
        h0[j] = (short)f2bfh(fmaxf(x0, 0.f));
      }
      *(bf16x8*)&As[r*32 + h] = h0;
    } else {
      const unsigned short* gA = A + (size_t)(m0 + sr)*256 + k0 + sc;
      gl_lds16(gA, lA);
    }
    gl_lds16(gB  + k0, lB);
    gl_lds16(gB2 + k0, lB2);
    __syncthreads();
    bf16x8 af[4], bfr[4];
    #pragma unroll
    for (int fi = 0; fi < 4; fi++)
      af[fi] = *(const bf16x8*)&As[(wm*64 + fi*16 + lrow)*32 + lkg*8];
    #pragma unroll
    for (int nf = 0; nf < 4; nf++)
      bfr[nf] = *(const bf16x8*)&Bs[(wn*64 + nf*16 + lrow)*32 + lkg*8];
    #pragma unroll
    for (int fi = 0; fi < 4; fi++)
      #pragma unroll
      for (int nf = 0; nf < 4; nf++)
        acc[fi][nf] = MFMA(af[fi], bfr[nf], acc[fi][nf]);
    __syncthreads();
  }

  if constexpr (MODE == 0){
    unsigned short* outp = (blockIdx.y==0)?o0:(blockIdx.y==1)?o1:(blockIdx.y==2)?o2:o3;
    #pragma unroll
    for (int fi=0; fi<4; fi++)
      #pragma unroll
      for (int nf=0; nf<4; nf++)
        #pragma unroll
        for (int r=0;r<4;r++){
          int row = m0 + wm*64 + fi*16 + lkg*4 + r;
          int col = wn*64 + nf*16 + lrow;            // 0..255
          outp[(size_t)row*256 + col] = f2bf(acc[fi][nf][r] + biasS[col]);
        }
  } else if constexpr (MODE == 2){
    const bool is_a1 = (blockIdx.y == 0);
    #pragma unroll
    for (int fi=0; fi<4; fi++){
      int g = (rowbase + m0 + wm*64 + fi*16) >> 4;   // point id (16 rows = 1 point)
      #pragma unroll
      for (int nf=0; nf<4; nf++){
        int colg = wn*64 + nf*16 + lrow;             // 0..255
        if (is_a1){
          float qv = bf2f(qg[(size_t)g*256 + colg]) + biasS[colg];   // biasS = c1
          #pragma unroll
          for (int r=0;r<4;r++){
            int rl_ = wm*64 + fi*16 + lkg*4 + r;
            int gi = gidxS[rl_];
            float a1 = acc[fi][nf][r] + qv - bf2f(kg[(size_t)gi*256 + colg]);
            o0[(size_t)(m0 + rl_)*256 + colg] = f2bfh(fmaxf(a1, 0.f));
          }
        } else {
          float bb = biasS[colg];                    // biasS = b2
          #pragma unroll
          for (int r=0;r<4;r++){
            int rl_ = wm*64 + fi*16 + lkg*4 + r;
            int gi = gidxS[rl_];
            float vpe = acc[fi][nf][r] + bb + bf2f(vb[(size_t)gi*256 + colg]);
            o1[(size_t)(m0 + rl_)*256 + colg] = f2bfh(vpe);
          }
        }
      }
    }
  } else if constexpr (MODE == 3){
    #pragma unroll
    for (int fi=0; fi<4; fi++){
      int g = (rowbase + m0 + wm*64 + fi*16) >> 4;
      #pragma unroll
      for (int nf=0; nf<4; nf++){
        int colg = wn*64 + nf*16 + lrow;             // 0..255
        float s[4], e[4];
        #pragma unroll
        for (int r=0;r<4;r++) s[r] = acc[fi][nf][r] + bias[colg]*0.0625f;  // bias = gb2
        float mx = fmaxf(fmaxf(s[0],s[1]), fmaxf(s[2],s[3]));
        mx = fmaxf(mx, __shfl_xor(mx,16,64));
        mx = fmaxf(mx, __shfl_xor(mx,32,64));
        float sm = 0.f;
        #pragma unroll
        for (int r=0;r<4;r++){ e[r] = __expf(s[r]-mx); sm += e[r]; }
        sm += __shfl_xor(sm,16,64);
        sm += __shfl_xor(sm,32,64);
        float rs = 1.f/sm, tsum = 0.f;
        #pragma unroll
        for (int r=0;r<4;r++){
          int rl_ = wm*64 + fi*16 + lkg*4 + r;
          tsum += (e[r]*rs) * bf2f(vper[(size_t)(m0 + rl_)*256 + colg]);
        }
        tsum += __shfl_xor(tsum,16,64);
        tsum += __shfl_xor(tsum,32,64);
        if (lkg == 0) o0[(size_t)g*256 + colg] = f2bf(tsum);
      }
    }
  } else {   // FIN
    #pragma unroll
    for (int fi=0; fi<4; fi++)
      #pragma unroll
      for (int nf=0; nf<4; nf++)
        #pragma unroll
        for (int r=0;r<4;r++){
          int row = m0 + wm*64 + fi*16 + lkg*4 + r;
          int col = wn*64 + nf*16 + lrow;
          fout[(size_t)row*256 + col] = acc[fi][nf][r] + bias[col]
                                      + bf2f(qg[(size_t)row*256 + col]);  // qg slot = scbuf
        }
  }
}

// ---------------- host ----------------
extern "C" void kernel_launch(void* const* d_in, const int* in_sizes, int n_in,
                              void* d_out, int out_size, void* d_ws, size_t ws_size,
                              hipStream_t stream){
  (void)in_sizes; (void)n_in; (void)out_size;
  const float* xyz  = (const float*)d_in[0];
  const float* feat = (const float*)d_in[1];
  const float* W1   = (const float*)d_in[2];
  const float* b1d  = (const float*)d_in[3];
  const float* W2   = (const float*)d_in[4];
  const float* b2d  = (const float*)d_in[5];
  const float* fc1w = (const float*)d_in[6];
  const float* fc1b = (const float*)d_in[7];
  const float* wq   = (const float*)d_in[8];
  const float* wk   = (const float*)d_in[9];
  const float* wv   = (const float*)d_in[10];
  const float* g1   = (const float*)d_in[11];
  const float* gb1  = (const float*)d_in[12];
  const float* g2   = (const float*)d_in[13];
  const float* gb2  = (const float*)d_in[14];
  const float* fc2w = (const float*)d_in[15];
  const float* fc2b = (const float*)d_in[16];
  const float* scw  = (const float*)d_in[17];
  const float* scb  = (const float*)d_in[18];

  char* ws = (char*)d_ws;
  size_t off = 0;
  auto alloc = [&](size_t bytes)->void*{ void* p = ws + off; off += (bytes + 255) & ~(size_t)255; return p; };
  unsigned short* Xb     = (unsigned short*)alloc((size_t)NTOT*256*2);  // reused as res
  unsigned short* qgb    = (unsigned short*)alloc((size_t)NTOT*256*2);
  unsigned short* kgb    = (unsigned short*)alloc((size_t)NTOT*256*2);
  unsigned short* vbb    = (unsigned short*)alloc((size_t)NTOT*256*2);
  unsigned short* scbuf  = (unsigned short*)alloc((size_t)NTOT*256*2);
  int*            gidxbuf= (int*)alloc((size_t)NROWS*4);
  float4*         relbuf = (float4*)alloc((size_t)NROWS*16);
  float4*         xyzw   = (float4*)alloc((size_t)NTOT*16);
  unsigned short* qkv2T  = (unsigned short*)alloc(1024*256*2);
  unsigned short* tmpWq  = (unsigned short*)alloc(256*256*2);
  unsigned short* tmpWk  = (unsigned short*)alloc(256*256*2);
  unsigned short* BposT  = (unsigned short*)alloc(512*256*2);
  unsigned short* g2sT   = (unsigned short*)alloc(256*256*2);
  unsigned short* fc2T   = (unsigned short*)alloc(256*256*2);
  float*          c1     = (float*)alloc(256*4);
  float*          cvec   = (float*)alloc(1024*4);
  unsigned short* res    = Xb;

  // adaptive chunk: a1 + vpe cost CR*1024 bytes (single chunk if ws allows)
  int CR = NROWS;
  while (CR > 16384 && off + (size_t)CR*1024 > ws_size) CR >>= 1;
  unsigned short* a1buf  = (unsigned short*)alloc((size_t)CR*256*2);
  unsigned short* vpebuf = (unsigned short*)alloc((size_t)CR*256*2);

  k_convert<<<4096, 256, 0, stream>>>(feat, Xb, NTOT*256);
  k_xyzw<<<64, 256, 0, stream>>>(xyz, xyzw);
  k_prep_mats<<<256, 256, 0, stream>>>(scw, g2, fc2w, W2, scb, qkv2T, g2sT, fc2T, BposT, cvec);
  k_prep_gemm<<<769, 256, 0, stream>>>(wq, wk, g1, W2, b2d, gb1, tmpWq, tmpWk, BposT, c1);
  k_prep_gemm2<<<769, 256, 0, stream>>>(fc1w, fc1b, wv, tmpWq, tmpWk, qkv2T, cvec);
  k_knn<<<4096, 256, 0, stream>>>(xyzw, gidxbuf, relbuf);

  k_mm<0><<<dim3(128, 4), 512, 0, stream>>>(Xb, qkv2T, 0, cvec, nullptr,
      nullptr, nullptr, nullptr, nullptr, nullptr, nullptr, nullptr,
      qgb, kgb, vbb, scbuf, nullptr, nullptr);

  for (int c0 = 0; c0 < NROWS; c0 += CR){
    k_mm<2><<<dim3(CR/128, 2), 512, 0, stream>>>(nullptr, BposT, c0, c1, b2d,
        qgb, kgb, vbb, relbuf, gidxbuf, W1, b1d,
        a1buf, vpebuf, nullptr, nullptr, nullptr, nullptr);
    k_mm<3><<<dim3(CR/128, 1), 512, 0, stream>>>(a1buf, g2sT, c0, gb2, nullptr,
        nullptr, nullptr, nullptr, nullptr, nullptr, nullptr, nullptr,
        res, nullptr, nullptr, nullptr, vpebuf, nullptr);
  }

  k_mm<4><<<dim3(128, 1), 512, 0, stream>>>(res, fc2T, 0, fc2b, nullptr,
      scbuf, nullptr, nullptr, nullptr, nullptr, nullptr, nullptr,
      nullptr, nullptr, nullptr, nullptr, nullptr, (float*)d_out);
}

// Round 14
// 439.584 us; speedup vs baseline: 2.1927x; 1.1003x over previous
//
#include <hip/hip_runtime.h>
#include <hip/hip_bf16.h>
#include <math.h>

typedef __attribute__((ext_vector_type(8))) short bf16x8;
typedef __attribute__((ext_vector_type(4))) float f32x4;
typedef __attribute__((ext_vector_type(4))) short s16x4;
typedef unsigned int u32;
typedef unsigned long long u64;

#define NBATCH 4
#define NPTS   4096
#define NTOT   (NBATCH*NPTS)     // 16384 points
#define NROWS  (NTOT*16)         // 262144 (point,neighbor) rows

__device__ __forceinline__ float bf2f(unsigned short h){
  unsigned int u = ((unsigned int)h) << 16;
  return __builtin_bit_cast(float, u);
}
__device__ __forceinline__ unsigned short f2bf(float f){
  unsigned int u = __builtin_bit_cast(unsigned int, f);
  u += 0x7FFFu + ((u >> 16) & 1u);   // RNE
  return (unsigned short)(u >> 16);
}
__device__ __forceinline__ unsigned short f2bfh(float f){   // HW cvt (RNE, pairs fuse to cvt_pk)
  return __bfloat16_as_ushort(__float2bfloat16(f));
}

#define MFMA(a,b,c) __builtin_amdgcn_mfma_f32_16x16x32_bf16((a),(b),(c),0,0,0)

typedef u32 __attribute__((address_space(1))) gas_u32;
typedef u32 __attribute__((address_space(3))) las_u32;
__device__ __forceinline__ void gl_lds16(const void* g, void* l){
  __builtin_amdgcn_global_load_lds((const gas_u32*)g, (las_u32*)l, 16, 0, 0);
}

// wave-internal LDS ordering fence (rule #18 pattern)
__device__ __forceinline__ void wfence(){
  asm volatile("s_waitcnt lgkmcnt(0)" ::: "memory");
  __builtin_amdgcn_sched_barrier(0);
}

// byte offset into a [row][256 bf16] LDS tile (512B row stride), XOR-swizzled
__device__ __forceinline__ unsigned int swz(int row, int kbyte){
  return (unsigned int)(row * 512) + (((unsigned int)kbyte) ^ (((unsigned int)row & 7u) << 4));
}

// ---------------- prep: features -> bf16 ----------------
__global__ __launch_bounds__(256) void k_convert(const float* __restrict__ x,
                                                 unsigned short* __restrict__ xb, int n){
  int i = (blockIdx.x * 256 + threadIdx.x) * 4;
  if (i < n){
    float4 v = *(const float4*)(x + i);
    s16x4 o;
    o[0] = (short)f2bf(v.x); o[1] = (short)f2bf(v.y);
    o[2] = (short)f2bf(v.z); o[3] = (short)f2bf(v.w);
    *(s16x4*)(xb + i) = o;
  }
}

// ---------------- prep: xyz -> float4 (x,y,z,|p|^2) ----------------
__global__ __launch_bounds__(256) void k_xyzw(const float* __restrict__ xyz,
                                              float4* __restrict__ xyzw){
  int i = blockIdx.x * 256 + threadIdx.x;   // 16384
  float x = xyz[i*3], y = xyz[i*3+1], z = xyz[i*3+2];
  xyzw[i] = make_float4(x, y, z, x*x + y*y + z*z);
}

// ---------------- prep: transposed bf16 weight copies ----------------
__global__ __launch_bounds__(256) void k_prep_mats(
    const float* __restrict__ scw, const float* __restrict__ g2,
    const float* __restrict__ fc2, const float* __restrict__ W2,
    const float* __restrict__ scb,
    unsigned short* __restrict__ qkv2T, unsigned short* __restrict__ g2sT,
    unsigned short* __restrict__ fc2T, unsigned short* __restrict__ BposT,
    float* __restrict__ cvec){
  int c = blockIdx.x, d = threadIdx.x;
  qkv2T[(768+c)*256 + d] = f2bf(scw[d*256 + c]);             // sc^T
  g2sT[c*256 + d]        = f2bf(g2[d*256 + c] * 0.0625f);    // fold 1/sqrt(DM)=1/16
  fc2T[c*256 + d]        = f2bf(fc2[d*256 + c]);
  BposT[(256+c)*256 + d] = f2bf(W2[d*256 + c]);              // W2^T (pe)
  if (d == 0) cvec[768 + c] = scb[c];
}

// ---------------- prep stage 1: Wqg = wq@g1, Wkg = wk@g1, W2g1, c1 ----------------
__global__ __launch_bounds__(256) void k_prep_gemm(
    const float* __restrict__ wq, const float* __restrict__ wk,
    const float* __restrict__ g1, const float* __restrict__ W2,
    const float* __restrict__ b2d, const float* __restrict__ gb1,
    unsigned short* __restrict__ tmpWq, unsigned short* __restrict__ tmpWk,
    unsigned short* __restrict__ BposT, float* __restrict__ c1){
  int c = threadIdx.x, bid = blockIdx.x;
  if (bid < 256){
    int d = bid; float acc = 0.f;
    for (int e=0;e<256;e++) acc += wq[d*256+e]*g1[e*256+c];
    tmpWq[c*256 + d] = f2bf(acc);
  } else if (bid < 512){
    int d = bid-256; float acc = 0.f;
    for (int e=0;e<256;e++) acc += wk[d*256+e]*g1[e*256+c];
    tmpWk[c*256 + d] = f2bf(acc);
  } else if (bid < 768){
    int d = bid-512; float acc = 0.f;
    for (int e=0;e<256;e++) acc += W2[d*256+e]*g1[e*256+c];
    BposT[c*256 + d] = f2bf(acc);
  } else {
    float acc = 0.f;
    for (int e=0;e<256;e++) acc += b2d[e]*g1[e*256+c];
    c1[c] = acc + gb1[c];
  }
}

// ---------------- prep stage 2: fold fc1 into QKV ----------------
__global__ __launch_bounds__(256) void k_prep_gemm2(
    const float* __restrict__ fc1w, const float* __restrict__ fc1b,
    const float* __restrict__ wv,
    const unsigned short* __restrict__ tmpWq, const unsigned short* __restrict__ tmpWk,
    unsigned short* __restrict__ qkv2T, float* __restrict__ cvec){
  int c = threadIdx.x, bid = blockIdx.x;
  if (bid < 256){
    int d = bid; float acc = 0.f;
    for (int e=0;e<256;e++) acc += fc1w[d*256+e]*bf2f(tmpWq[c*256+e]);
    qkv2T[c*256 + d] = f2bf(acc);
  } else if (bid < 512){
    int d = bid-256; float acc = 0.f;
    for (int e=0;e<256;e++) acc += fc1w[d*256+e]*bf2f(tmpWk[c*256+e]);
    qkv2T[(256+c)*256 + d] = f2bf(acc);
  } else if (bid < 768){
    int d = bid-512; float acc = 0.f;
    for (int e=0;e<256;e++) acc += fc1w[d*256+e]*wv[e*256+c];
    qkv2T[(512+c)*256 + d] = f2bf(acc);
  } else {
    float aq=0.f, ak=0.f, av=0.f;
    for (int e=0;e<256;e++){
      float fb = fc1b[e];
      aq += fb*bf2f(tmpWq[c*256+e]);
      ak += fb*bf2f(tmpWk[c*256+e]);
      av += fb*wv[e*256+c];
    }
    cvec[c] = aq; cvec[256+c] = ak; cvec[512+c] = av;
  }
}

// ======== kNN: radix rank-select, 2 full scans (r13 version, 140 us) ========
__device__ __forceinline__ u32 fmap(float d){
  u32 u = __builtin_bit_cast(u32, d);
  return ((int)u < 0) ? ~u : (u | 0x80000000u);
}

__device__ __forceinline__ void find_thresh(const int* hist, int lane, int need,
                                            int* e_out, int* c_out){
  int h0 = hist[lane*4], h1 = hist[lane*4+1], h2 = hist[lane*4+2], h3 = hist[lane*4+3];
  int ps = h0 + h1 + h2 + h3;
  int incl = ps;
  #pragma unroll
  for (int d = 1; d < 64; d <<= 1){
    int tv = __shfl_up(incl, d, 64);
    if (lane >= d) incl += tv;
  }
  int excl = incl - ps;
  int b0 = excl, b1 = excl + h0, b2 = b1 + h1, b3 = b2 + h2;
  bool f0 = (b0 < need) && (b0 + h0 >= need);
  bool f1 = (b1 < need) && (b1 + h1 >= need);
  bool f2 = (b2 < need) && (b2 + h2 >= need);
  bool f3 = (b3 < need) && (b3 + h3 >= need);
  int e_loc = f0 ? lane*4 : f1 ? lane*4+1 : f2 ? lane*4+2 : lane*4+3;
  int c_loc = f0 ? b0 : f1 ? b1 : f2 ? b2 : b3;
  u64 mk = __ballot(f0 | f1 | f2 | f3);
  int wl = __ffsll(mk) - 1;
  *e_out = __shfl(e_loc, wl, 64);
  *c_out = __shfl(c_loc, wl, 64);
}

__device__ __forceinline__ void find_thresh4(const int* hA, int lane, int need,
                                             int* e_out, int* c_out){
  int h[4];
  #pragma unroll
  for (int j=0;j<4;j++){
    int bin = lane*4+j;
    h[j] = hA[bin]
         + hA[256 + ((bin+8)&255)]
         + hA[512 + ((bin+16)&255)]
         + hA[768 + ((bin+24)&255)];
  }
  int ps = h[0] + h[1] + h[2] + h[3];
  int incl = ps;
  #pragma unroll
  for (int d = 1; d < 64; d <<= 1){
    int tv = __shfl_up(incl, d, 64);
    if (lane >= d) incl += tv;
  }
  int excl = incl - ps;
  int b0 = excl, b1 = excl + h[0], b2 = b1 + h[1], b3 = b2 + h[2];
  bool f0 = (b0 < need) && (b0 + h[0] >= need);
  bool f1 = (b1 < need) && (b1 + h[1] >= need);
  bool f2 = (b2 < need) && (b2 + h[2] >= need);
  bool f3 = (b3 < need) && (b3 + h[3] >= need);
  int e_loc = f0 ? lane*4 : f1 ? lane*4+1 : f2 ? lane*4+2 : lane*4+3;
  int c_loc = f0 ? b0 : f1 ? b1 : f2 ? b2 : b3;
  u64 mk = __ballot(f0 | f1 | f2 | f3);
  int wl = __ffsll(mk) - 1;
  *e_out = __shfl(e_loc, wl, 64);
  *c_out = __shfl(c_loc, wl, 64);
}

__global__ __launch_bounds__(256) void k_knn(const float4* __restrict__ xyzw,
                                             int* __restrict__ gidxbuf,
                                             float4* __restrict__ relbuf){
  __shared__ int histA[4][1024];    // 16KB
  __shared__ int histB[4][256];     // 4KB

  int t = threadIdx.x, lane = t & 63, wv = t >> 6;
  int widx = blockIdx.x * 4 + wv;          // 0..16383
  int b = widx >> 12, n = widx & 4095;
  const float4* xb = xyzw + (size_t)b * NPTS;
  float4 P = xb[n];
  float x2n = P.w;
  int* hA = histA[wv]; int* hB = histB[wv];

  #pragma unroll
  for (int j = 0; j < 16; j++) hA[lane*16+j] = 0;
  #pragma unroll
  for (int j = 0; j < 4; j++)  hB[lane*4+j] = 0;
  wfence();

  int cp = lane >> 4;
  int cpoff = cp*256, cprot = cp*8;

  for (int it = 0; it < 64; it += 2){
    float4 Q0 = xb[it*64 + lane];
    float4 Q1 = xb[it*64 + 64 + lane];
    float d0 = x2n + Q0.w - 2.0f*(P.x*Q0.x + P.y*Q0.y + P.z*Q0.z);
    float d1 = x2n + Q1.w - 2.0f*(P.x*Q1.x + P.y*Q1.y + P.z*Q1.z);
    int b0 = (int)(fmap(d0) >> 24), b1 = (int)(fmap(d1) >> 24);
    atomicAdd(&hA[cpoff + ((b0 + cprot)&255)], 1);
    atomicAdd(&hA[cpoff + ((b1 + cprot)&255)], 1);
  }
  wfence();
  int e1, c0dummy;
  find_thresh4(hA, lane, 16, &e1, &c0dummy);
  wfence();

  u32* lstE_u = (u32*)&hA[0];
  int* lstE_m = &hA[128];
  u32* lstT_u = (u32*)&hA[256];
  int* lstT_m = &hA[320];

  int base = 0, Lc = 0;
  size_t orow = (size_t)widx * 16;
  for (int it = 0; it < 64; it++){
    int m = it*64 + lane;
    float4 Q = xb[m];
    u32 u = fmap(x2n + Q.w - 2.0f*(P.x*Q.x + P.y*Q.y + P.z*Q.z));
    int hi = (int)(u >> 24);
    bool def = hi < e1;
    bool bnd = hi == e1;
    u64 mkd = __ballot(def);
    if (def){
      int slot = base + __popcll(mkd & ((1ULL << lane) - 1ULL));
      gidxbuf[orow + slot] = b*NPTS + m;
      relbuf[orow + slot]  = make_float4(P.x - Q.x, P.y - Q.y, P.z - Q.z, 0.f);
    }
    base += __popcll(mkd);
    u64 mkb = __ballot(bnd);
    if (bnd){
      int sl = Lc + __popcll(mkb & ((1ULL << lane) - 1ULL));
      if (sl < 128){ lstE_u[sl] = u; lstE_m[sl] = m; }
      atomicAdd(&hB[(u >> 16) & 0xFF], 1);
    }
    Lc += __popcll(mkb);
  }
  wfence();
  int c0 = base;
  int m1, cc;
  find_thresh(hB, lane, 16 - c0, &m1, &cc);
  int c1 = c0 + cc;

  int nt = 0;
  if (Lc <= 128){
    int eb = c0;
    for (int ch = 0; ch < 128; ch += 64){
      int idx = ch + lane;
      bool valid = idx < Lc;
      u32 u = valid ? lstE_u[idx] : 0xFFFFFFFFu;
      int mid = valid ? (int)((u >> 16) & 0xFF) : 999;
      bool lt = valid && (mid < m1);
      u64 mk = __ballot(lt);
      if (lt){
        int slot = eb + __popcll(mk & ((1ULL << lane) - 1ULL));
        int m = lstE_m[idx];
        float4 Q = xb[m];
        gidxbuf[orow + slot] = b*NPTS + m;
        relbuf[orow + slot]  = make_float4(P.x - Q.x, P.y - Q.y, P.z - Q.z, 0.f);
      }
      eb += __popcll(mk);
      bool tie = valid && (mid == m1);
      u64 mkt = __ballot(tie);
      if (tie){
        int sl = nt + __popcll(mkt & ((1ULL << lane) - 1ULL));
        if (sl < 64){ lstT_u[sl] = u; lstT_m[sl] = lstE_m[idx]; }
      }
      nt += __popcll(mkt);
      if (Lc <= 64) break;
    }
  } else {
    int eb = c0;
    for (int it = 0; it < 64; it++){
      int m = it*64 + lane;
      float4 Q = xb[m];
      u32 u = fmap(x2n + Q.w - 2.0f*(P.x*Q.x + P.y*Q.y + P.z*Q.z));
      bool inb = ((int)(u >> 24) == e1);
      int mid = inb ? (int)((u >> 16) & 0xFF) : 999;
      bool lt = inb && (mid < m1);
      u64 mk = __ballot(lt);
      if (lt){
        int slot = eb + __popcll(mk & ((1ULL << lane) - 1ULL));
        gidxbuf[orow + slot] = b*NPTS + m;
        relbuf[orow + slot]  = make_float4(P.x - Q.x, P.y - Q.y, P.z - Q.z, 0.f);
      }
      eb += __popcll(mk);
      bool tie = inb && (mid == m1);
      u64 mkt = __ballot(tie);
      if (tie){
        int sl = nt + __popcll(mkt & ((1ULL << lane) - 1ULL));
        if (sl < 64){ lstT_u[sl] = u; lstT_m[sl] = m; }
      }
      nt += __popcll(mkt);
    }
  }
  wfence();
  if (nt > 64) nt = 64;

  int r2 = 16 - c1;
  u32 lu = (lane < nt) ? lstT_u[lane] : 0xFFFFFFFFu;
  int lm = (lane < nt) ? lstT_m[lane] : 0x7FFFFFFF;
  bool popped = false;
  for (int r = 0; r < r2; r++){
    u32 ku = popped ? 0xFFFFFFFFu : lu;
    int km = popped ? 0x7FFFFFFF : lm;
    #pragma unroll
    for (int off = 32; off >= 1; off >>= 1){
      u32 ou = __shfl_xor(ku, off, 64);
      int om = __shfl_xor(km, off, 64);
      if (ou < ku || (ou == ku && om < km)){ ku = ou; km = om; }
    }
    bool mine = !popped && (lane < nt) && (lu == ku) && (lm == km);
    u64 mk = __ballot(mine);
    int wl = __ffsll(mk) - 1;
    if (lane == wl){
      popped = true;
      float4 Q = xb[km];
      gidxbuf[orow + c1 + r] = b*NPTS + km;
      relbuf[orow + c1 + r]  = make_float4(P.x - Q.x, P.y - Q.y, P.z - Q.z, 0.f);
    }
  }
}

// ============ flat GEMM (512 thr, BM=128, BN=256): MODE 0 = QKV, MODE 4 = FIN ============
template<int MODE>
__global__ __launch_bounds__(512) void k_mm(
    const unsigned short* __restrict__ A, const unsigned short* __restrict__ BT,
    const float* __restrict__ bias,
    unsigned short* __restrict__ o0, unsigned short* __restrict__ o1,
    unsigned short* __restrict__ o2, unsigned short* __restrict__ o3,
    const unsigned short* __restrict__ scbuf, float* __restrict__ fout){
  __shared__ unsigned short As[4096];   // 128 x 32
  __shared__ unsigned short Bs[8192];   // 256 x 32
  __shared__ float  biasS[256];

  int t = threadIdx.x;
  int lane = t & 63, w = t >> 6;
  int wm = w >> 2, wn = w & 3;          // 2 x 4 wave grid
  int lrow = lane & 15, lkg = lane >> 4;
  int m0 = blockIdx.x * 128, n0 = blockIdx.y * 256;
  if (t < 256) biasS[t] = bias[n0 + t];

  int sr = t >> 2, sc = (t & 3) * 8;
  unsigned short* lA  = As + (w << 9);
  unsigned short* lB  = Bs + (w << 9);
  unsigned short* lB2 = Bs + 4096 + (w << 9);
  const unsigned short* gB  = BT + (size_t)(n0 + sr)*256 + sc;
  const unsigned short* gB2 = BT + (size_t)(n0 + 128 + sr)*256 + sc;

  f32x4 acc[4][4] = {};
  for (int k0 = 0; k0 < 256; k0 += 32){
    const unsigned short* gA = A + (size_t)(m0 + sr)*256 + k0 + sc;
    gl_lds16(gA, lA);
    gl_lds16(gB  + k0, lB);
    gl_lds16(gB2 + k0, lB2);
    __syncthreads();
    bf16x8 af[4], bfr[4];
    #pragma unroll
    for (int fi = 0; fi < 4; fi++)
      af[fi] = *(const bf16x8*)&As[(wm*64 + fi*16 + lrow)*32 + lkg*8];
    #pragma unroll
    for (int nf = 0; nf < 4; nf++)
      bfr[nf] = *(const bf16x8*)&Bs[(wn*64 + nf*16 + lrow)*32 + lkg*8];
    #pragma unroll
    for (int fi = 0; fi < 4; fi++)
      #pragma unroll
      for (int nf = 0; nf < 4; nf++)
        acc[fi][nf] = MFMA(af[fi], bfr[nf], acc[fi][nf]);
    __syncthreads();
  }

  if constexpr (MODE == 0){
    unsigned short* outp = (blockIdx.y==0)?o0:(blockIdx.y==1)?o1:(blockIdx.y==2)?o2:o3;
    #pragma unroll
    for (int fi=0; fi<4; fi++)
      #pragma unroll
      for (int nf=0; nf<4; nf++)
        #pragma unroll
        for (int r=0;r<4;r++){
          int row = m0 + wm*64 + fi*16 + lkg*4 + r;
          int col = wn*64 + nf*16 + lrow;
          outp[(size_t)row*256 + col] = f2bf(acc[fi][nf][r] + biasS[col]);
        }
  } else {   // FIN
    #pragma unroll
    for (int fi=0; fi<4; fi++)
      #pragma unroll
      for (int nf=0; nf<4; nf++)
        #pragma unroll
        for (int r=0;r<4;r++){
          int row = m0 + wm*64 + fi*16 + lkg*4 + r;
          int col = wn*64 + nf*16 + lrow;
          fout[(size_t)row*256 + col] = acc[fi][nf][r] + biasS[col]
                                      + bf2f(scbuf[(size_t)row*256 + col]);
        }
  }
}

// ============ fused G2a->G3->G2b: 256 thr (4 waves, 1x4), BM=64, BN=256 ============
// a1 tile lives in LDS (never hits HBM). Phases:
//  A: posg = H@W2g1; a1 = relu(posg + qg - kg + c1) -> a1s (swizzled)
//  B: s = a1s @ (g2/16); softmax over K=16 -> attn (overwrites acc3 regs)
//  C: pe = H@W2; res = sum_k attn*(pe + b2 + v[gidx])
// LDS 61696B -> 2 blocks/CU (barrier overlap across blocks).
__global__ __launch_bounds__(256) void k_fused(
    const unsigned short* __restrict__ BposT, const unsigned short* __restrict__ g2sT,
    const unsigned short* __restrict__ qg, const unsigned short* __restrict__ kg,
    const unsigned short* __restrict__ vb,
    const float4* __restrict__ relbuf, const int* __restrict__ gidxbuf,
    const float* __restrict__ W1, const float* __restrict__ b1d,
    const float* __restrict__ c1, const float* __restrict__ b2d,
    const float* __restrict__ gb2,
    unsigned short* __restrict__ res){
  extern __shared__ char smem[];
  char*           a1sB  = smem;                             // 32KB: 64 rows x 512B, swizzled
  unsigned short* As    = (unsigned short*)(smem + 32768);  // 4KB: 64x32 (H slices)
  unsigned short* Bs    = (unsigned short*)(smem + 36864);  // 16KB: 256x32
  float4*         W1s4  = (float4*)(smem + 53248);          // 4KB
  float4*         relS  = (float4*)(smem + 57344);          // 1KB
  int*            gidxS = (int*)(smem + 58368);             // 256B
  float*          c1s   = (float*)(smem + 58624);           // 1KB
  float*          b2s   = (float*)(smem + 59648);           // 1KB
  float*          gb2s  = (float*)(smem + 60672);           // 1KB -> total 61696

  int t = threadIdx.x;
  int lane = t & 63, w = t >> 6;        // 4 waves
  int wn = w;                           // wave owns cols [wn*64, wn*64+64)
  int lrow = lane & 15, lkg = lane >> 4;
  int bx = blockIdx.x;
  { int gx = gridDim.x; bx = (bx & 7) * (gx >> 3) + (bx >> 3); }   // XCD swizzle
  int m0 = bx * 64;                     // 4 points per block

  if (t < 64){
    relS[t]  = relbuf[(size_t)m0 + t];
    gidxS[t] = gidxbuf[(size_t)m0 + t];
  }
  W1s4[t] = make_float4(W1[t], W1[256+t], W1[512+t], b1d[t]);
  c1s[t] = c1[t]; b2s[t] = b2d[t]; gb2s[t] = gb2[t]*0.0625f;
  __syncthreads();
  float4 rl0 = relS[t >> 2];            // loop-invariant

  int sr = t >> 2, sc = (t & 3) * 8;    // staging coords (sr 0..63)
  // Bs quarter bases: quarter q rows [q*64, q*64+64); wave w lanes cover rows w*16..+16
  unsigned short* lBq[4];
  #pragma unroll
  for (int q = 0; q < 4; q++) lBq[q] = Bs + q*2048 + w*512;

  const unsigned short* BTa = BposT;                       // W2g1^T
  const unsigned short* BTb = g2sT;                        // (g2/16)^T
  const unsigned short* BTc = BposT + (size_t)256*256;     // W2^T

  // ---------------- phase A ----------------
  f32x4 acc[4][4] = {};
  for (int k0 = 0; k0 < 256; k0 += 32){
    { // H rows [0,64) cols [k0,k0+32)
      int r = sr, h = (t & 3) << 3;
      bf16x8 h0;
      #pragma unroll
      for (int j = 0; j < 8; j++){
        int c = k0 + h + j;
        float4 wa = W1s4[c];
        float x0 = rl0.x*wa.x + rl0.y*wa.y + rl0.z*wa.z + wa.w;
        h0[j] = (short)f2bfh(fmaxf(x0, 0.f));
      }
      *(bf16x8*)&As[r*32 + h] = h0;
    }
    #pragma unroll
    for (int q = 0; q < 4; q++)
      gl_lds16(BTa + (size_t)(q*64 + sr)*256 + k0 + sc, lBq[q]);
    __syncthreads();
    bf16x8 af[4], bfr[4];
    #pragma unroll
    for (int fi = 0; fi < 4; fi++)
      af[fi] = *(const bf16x8*)&As[(fi*16 + lrow)*32 + lkg*8];
    #pragma unroll
    for (int nf = 0; nf < 4; nf++)
      bfr[nf] = *(const bf16x8*)&Bs[(wn*64 + nf*16 + lrow)*32 + lkg*8];
    #pragma unroll
    for (int fi = 0; fi < 4; fi++)
      #pragma unroll
      for (int nf = 0; nf < 4; nf++)
        acc[fi][nf] = MFMA(af[fi], bfr[nf], acc[fi][nf]);
    __syncthreads();
  }
  // epilogue A: a1 -> a1s (swizzled)
  #pragma unroll
  for (int fi=0; fi<4; fi++){
    int g = (m0 >> 4) + fi;             // point id
    #pragma unroll
    for (int nf=0; nf<4; nf++){
      int colg = wn*64 + nf*16 + lrow;
      float qv = bf2f(qg[(size_t)g*256 + colg]) + c1s[colg];
      #pragma unroll
      for (int r=0;r<4;r++){
        int rl_ = fi*16 + lkg*4 + r;
        float a1 = acc[fi][nf][r] + qv - bf2f(kg[(size_t)gidxS[rl_]*256 + colg]);
        *(unsigned short*)(a1sB + swz(rl_, colg*2)) = f2bfh(fmaxf(a1, 0.f));
      }
    }
  }
  __syncthreads();                      // a1s visible

  // ---------------- phase B ----------------
  f32x4 acc3[4][4] = {};
  for (int k0 = 0; k0 < 256; k0 += 32){
    #pragma unroll
    for (int q = 0; q < 4; q++)
      gl_lds16(BTb + (size_t)(q*64 + sr)*256 + k0 + sc, lBq[q]);
    __syncthreads();
    bf16x8 af[4], bfr[4];
    #pragma unroll
    for (int fi = 0; fi < 4; fi++)
      af[fi] = *(const bf16x8*)(a1sB + swz(fi*16 + lrow, k0*2 + lkg*16));
    #pragma unroll
    for (int nf = 0; nf < 4; nf++)
      bfr[nf] = *(const bf16x8*)&Bs[(wn*64 + nf*16 + lrow)*32 + lkg*8];
    #pragma unroll
    for (int fi = 0; fi < 4; fi++)
      #pragma unroll
      for (int nf = 0; nf < 4; nf++)
        acc3[fi][nf] = MFMA(af[fi], bfr[nf], acc3[fi][nf]);
    __syncthreads();
  }
  // softmax per fragment (one point per fi; 16 rows = lkg*4+r over shfl 16/32)
  #pragma unroll
  for (int fi=0; fi<4; fi++)
    #pragma unroll
    for (int nf=0; nf<4; nf++){
      int colg = wn*64 + nf*16 + lrow;
      float s[4], e[4];
      #pragma unroll
      for (int r=0;r<4;r++) s[r] = acc3[fi][nf][r] + gb2s[colg];
      float mx = fmaxf(fmaxf(s[0],s[1]), fmaxf(s[2],s[3]));
      mx = fmaxf(mx, __shfl_xor(mx,16,64));
      mx = fmaxf(mx, __shfl_xor(mx,32,64));
      float sm = 0.f;
      #pragma unroll
      for (int r=0;r<4;r++){ e[r] = __expf(s[r]-mx); sm += e[r]; }
      sm += __shfl_xor(sm,16,64);
      sm += __shfl_xor(sm,32,64);
      float rs = 1.f/sm;
      #pragma unroll
      for (int r=0;r<4;r++) acc3[fi][nf][r] = e[r]*rs;   // attn in-place
    }

  // ---------------- phase C ----------------
  f32x4 acc2[4][4] = {};
  for (int k0 = 0; k0 < 256; k0 += 32){
    { // H again
      int r = sr, h = (t & 3) << 3;
      bf16x8 h0;
      #pragma unroll
      for (int j = 0; j < 8; j++){
        int c = k0 + h + j;
        float4 wa = W1s4[c];
        float x0 = rl0.x*wa.x + rl0.y*wa.y + rl0.z*wa.z + wa.w;
        h0[j] = (short)f2bfh(fmaxf(x0, 0.f));
      }
      *(bf16x8*)&As[r*32 + h] = h0;
    }
    #pragma unroll
    for (int q = 0; q < 4; q++)
      gl_lds16(BTc + (size_t)(q*64 + sr)*256 + k0 + sc, lBq[q]);
    __syncthreads();
    bf16x8 af[4], bfr[4];
    #pragma unroll
    for (int fi = 0; fi < 4; fi++)
      af[fi] = *(const bf16x8*)&As[(fi*16 + lrow)*32 + lkg*8];
    #pragma unroll
    for (int nf = 0; nf < 4; nf++)
      bfr[nf] = *(const bf16x8*)&Bs[(wn*64 + nf*16 + lrow)*32 + lkg*8];
    #pragma unroll
    for (int fi = 0; fi < 4; fi++)
      #pragma unroll
      for (int nf = 0; nf < 4; nf++)
        acc2[fi][nf] = MFMA(af[fi], bfr[nf], acc2[fi][nf]);
    __syncthreads();
  }
  // epilogue C: res = sum_k attn * (pe + b2 + v[gidx])
  #pragma unroll
  for (int fi=0; fi<4; fi++){
    int g = (m0 >> 4) + fi;
    #pragma unroll
    for (int nf=0; nf<4; nf++){
      int colg = wn*64 + nf*16 + lrow;
      float bb = b2s[colg];
      float tsum = 0.f;
      #pragma unroll
      for (int r=0;r<4;r++){
        int rl_ = fi*16 + lkg*4 + r;
        float vv = acc2[fi][nf][r] + bb + bf2f(vb[(size_t)gidxS[rl_]*256 + colg]);
        tsum += acc3[fi][nf][r] * vv;
      }
      tsum += __shfl_xor(tsum,16,64);
      tsum += __shfl_xor(tsum,32,64);
      if (lkg == 0) res[(size_t)g*256 + colg] = f2bf(tsum);
    }
  }
}

// ---------------- host ----------------
extern "C" void kernel_launch(void* const* d_in, const int* in_sizes, int n_in,
                              void* d_out, int out_size, void* d_ws, size_t ws_size,
                              hipStream_t stream){
  (void)in_sizes; (void)n_in; (void)out_size; (void)ws_size;
  const float* xyz  = (const float*)d_in[0];
  const float* feat = (const float*)d_in[1];
  const float* W1   = (const float*)d_in[2];
  const float* b1d  = (const float*)d_in[3];
  const float* W2   = (const float*)d_in[4];
  const float* b2d  = (const float*)d_in[5];
  const float* fc1w = (const float*)d_in[6];
  const float* fc1b = (const float*)d_in[7];
  const float* wq   = (const float*)d_in[8];
  const float* wk   = (const float*)d_in[9];
  const float* wv   = (const float*)d_in[10];
  const float* g1   = (const float*)d_in[11];
  const float* gb1  = (const float*)d_in[12];
  const float* g2   = (const float*)d_in[13];
  const float* gb2  = (const float*)d_in[14];
  const float* fc2w = (const float*)d_in[15];
  const float* fc2b = (const float*)d_in[16];
  const float* scw  = (const float*)d_in[17];
  const float* scb  = (const float*)d_in[18];

  char* ws = (char*)d_ws;
  size_t off = 0;
  auto alloc = [&](size_t bytes)->void*{ void* p = ws + off; off += (bytes + 255) & ~(size_t)255; return p; };
  unsigned short* Xb     = (unsigned short*)alloc((size_t)NTOT*256*2);  // reused as res
  unsigned short* qgb    = (unsigned short*)alloc((size_t)NTOT*256*2);
  unsigned short* kgb    = (unsigned short*)alloc((size_t)NTOT*256*2);
  unsigned short* vbb    = (unsigned short*)alloc((size_t)NTOT*256*2);
  unsigned short* scbuf  = (unsigned short*)alloc((size_t)NTOT*256*2);
  int*            gidxbuf= (int*)alloc((size_t)NROWS*4);
  float4*         relbuf = (float4*)alloc((size_t)NROWS*16);
  float4*         xyzw   = (float4*)alloc((size_t)NTOT*16);
  unsigned short* qkv2T  = (unsigned short*)alloc(1024*256*2);
  unsigned short* tmpWq  = (unsigned short*)alloc(256*256*2);
  unsigned short* tmpWk  = (unsigned short*)alloc(256*256*2);
  unsigned short* BposT  = (unsigned short*)alloc(512*256*2);
  unsigned short* g2sT   = (unsigned short*)alloc(256*256*2);
  unsigned short* fc2T   = (unsigned short*)alloc(256*256*2);
  float*          c1     = (float*)alloc(256*4);
  float*          cvec   = (float*)alloc(1024*4);
  unsigned short* res    = Xb;   // alias: Xb dead after k_mm<0>

  k_convert<<<4096, 256, 0, stream>>>(feat, Xb, NTOT*256);
  k_xyzw<<<64, 256, 0, stream>>>(xyz, xyzw);
  k_prep_mats<<<256, 256, 0, stream>>>(scw, g2, fc2w, W2, scb, qkv2T, g2sT, fc2T, BposT, cvec);
  k_prep_gemm<<<769, 256, 0, stream>>>(wq, wk, g1, W2, b2d, gb1, tmpWq, tmpWk, BposT, c1);
  k_prep_gemm2<<<769, 256, 0, stream>>>(fc1w, fc1b, wv, tmpWq, tmpWk, qkv2T, cvec);
  k_knn<<<4096, 256, 0, stream>>>(xyzw, gidxbuf, relbuf);

  k_mm<0><<<dim3(128, 4), 512, 0, stream>>>(Xb, qkv2T, cvec,
      qgb, kgb, vbb, scbuf, nullptr, nullptr);

  hipFuncSetAttribute((const void*)k_fused, hipFuncAttributeMaxDynamicSharedMemorySize, 61696);
  k_fused<<<dim3(NROWS/64), 256, 61696, stream>>>(BposT, g2sT, qgb, kgb, vbb,
      relbuf, gidxbuf, W1, b1d, c1, b2d, gb2, res);

  k_mm<4><<<dim3(128, 1), 512, 0, stream>>>(res, fc2T, fc2b,
      nullptr, nullptr, nullptr, nullptr, scbuf, (float*)d_out);
}

// Round 16
// 439.060 us; speedup vs baseline: 2.1954x; 1.0012x over previous
//
#include <hip/hip_runtime.h>
#include <hip/hip_bf16.h>
#include <math.h>

typedef __attribute__((ext_vector_type(8))) short bf16x8;
typedef __attribute__((ext_vector_type(4))) float f32x4;
typedef __attribute__((ext_vector_type(4))) short s16x4;
typedef unsigned int u32;
typedef unsigned long long u64;

#define NBATCH 4
#define NPTS   4096
#define NTOT   (NBATCH*NPTS)     // 16384 points
#define NROWS  (NTOT*16)         // 262144 (point,neighbor) rows

__device__ __forceinline__ float bf2f(unsigned short h){
  unsigned int u = ((unsigned int)h) << 16;
  return __builtin_bit_cast(float, u);
}
__device__ __forceinline__ unsigned short f2bf(float f){
  unsigned int u = __builtin_bit_cast(unsigned int, f);
  u += 0x7FFFu + ((u >> 16) & 1u);   // RNE
  return (unsigned short)(u >> 16);
}
__device__ __forceinline__ unsigned short f2bfh(float f){   // HW cvt (RNE, pairs fuse to cvt_pk)
  return __bfloat16_as_ushort(__float2bfloat16(f));
}

#define MFMA(a,b,c) __builtin_amdgcn_mfma_f32_16x16x32_bf16((a),(b),(c),0,0,0)

typedef u32 __attribute__((address_space(1))) gas_u32;
typedef u32 __attribute__((address_space(3))) las_u32;
__device__ __forceinline__ void gl_lds16(const void* g, void* l){
  __builtin_amdgcn_global_load_lds((const gas_u32*)g, (las_u32*)l, 16, 0, 0);
}

// wave-internal LDS ordering fence (rule #18 pattern)
__device__ __forceinline__ void wfence(){
  asm volatile("s_waitcnt lgkmcnt(0)" ::: "memory");
  __builtin_amdgcn_sched_barrier(0);
}

// byte offset into a [row][256 bf16] LDS tile (512B row stride), XOR-swizzled
__device__ __forceinline__ unsigned int swz(int row, int kbyte){
  return (unsigned int)(row * 512) + (((unsigned int)kbyte) ^ (((unsigned int)row & 7u) << 4));
}

// ---------------- prep: features -> bf16 ----------------
__global__ __launch_bounds__(256) void k_convert(const float* __restrict__ x,
                                                 unsigned short* __restrict__ xb, int n){
  int i = (blockIdx.x * 256 + threadIdx.x) * 4;
  if (i < n){
    float4 v = *(const float4*)(x + i);
    s16x4 o;
    o[0] = (short)f2bf(v.x); o[1] = (short)f2bf(v.y);
    o[2] = (short)f2bf(v.z); o[3] = (short)f2bf(v.w);
    *(s16x4*)(xb + i) = o;
  }
}

// ---------------- prep: xyz -> float4 (x,y,z,|p|^2) ----------------
__global__ __launch_bounds__(256) void k_xyzw(const float* __restrict__ xyz,
                                              float4* __restrict__ xyzw){
  int i = blockIdx.x * 256 + threadIdx.x;   // 16384
  float x = xyz[i*3], y = xyz[i*3+1], z = xyz[i*3+2];
  xyzw[i] = make_float4(x, y, z, x*x + y*y + z*z);
}

// ---------------- prep: transposed bf16 weight copies ----------------
__global__ __launch_bounds__(256) void k_prep_mats(
    const float* __restrict__ scw, const float* __restrict__ g2,
    const float* __restrict__ fc2, const float* __restrict__ W2,
    const float* __restrict__ scb,
    unsigned short* __restrict__ qkv2T, unsigned short* __restrict__ g2sT,
    unsigned short* __restrict__ fc2T, unsigned short* __restrict__ BposT,
    float* __restrict__ cvec){
  int c = blockIdx.x, d = threadIdx.x;
  qkv2T[(768+c)*256 + d] = f2bf(scw[d*256 + c]);             // sc^T
  g2sT[c*256 + d]        = f2bf(g2[d*256 + c] * 0.0625f);    // fold 1/sqrt(DM)=1/16
  fc2T[c*256 + d]        = f2bf(fc2[d*256 + c]);
  BposT[(256+c)*256 + d] = f2bf(W2[d*256 + c]);              // W2^T (pe)
  if (d == 0) cvec[768 + c] = scb[c];
}

// ---------------- prep stage 1: Wqg = wq@g1, Wkg = wk@g1, W2g1, c1 ----------------
__global__ __launch_bounds__(256) void k_prep_gemm(
    const float* __restrict__ wq, const float* __restrict__ wk,
    const float* __restrict__ g1, const float* __restrict__ W2,
    const float* __restrict__ b2d, const float* __restrict__ gb1,
    unsigned short* __restrict__ tmpWq, unsigned short* __restrict__ tmpWk,
    unsigned short* __restrict__ BposT, float* __restrict__ c1){
  int c = threadIdx.x, bid = blockIdx.x;
  if (bid < 256){
    int d = bid; float acc = 0.f;
    for (int e=0;e<256;e++) acc += wq[d*256+e]*g1[e*256+c];
    tmpWq[c*256 + d] = f2bf(acc);
  } else if (bid < 512){
    int d = bid-256; float acc = 0.f;
    for (int e=0;e<256;e++) acc += wk[d*256+e]*g1[e*256+c];
    tmpWk[c*256 + d] = f2bf(acc);
  } else if (bid < 768){
    int d = bid-512; float acc = 0.f;
    for (int e=0;e<256;e++) acc += W2[d*256+e]*g1[e*256+c];
    BposT[c*256 + d] = f2bf(acc);
  } else {
    float acc = 0.f;
    for (int e=0;e<256;e++) acc += b2d[e]*g1[e*256+c];
    c1[c] = acc + gb1[c];
  }
}

// ---------------- prep stage 2: fold fc1 into QKV ----------------
__global__ __launch_bounds__(256) void k_prep_gemm2(
    const float* __restrict__ fc1w, const float* __restrict__ fc1b,
    const float* __restrict__ wv,
    const unsigned short* __restrict__ tmpWq, const unsigned short* __restrict__ tmpWk,
    unsigned short* __restrict__ qkv2T, float* __restrict__ cvec){
  int c = threadIdx.x, bid = blockIdx.x;
  if (bid < 256){
    int d = bid; float acc = 0.f;
    for (int e=0;e<256;e++) acc += fc1w[d*256+e]*bf2f(tmpWq[c*256+e]);
    qkv2T[c*256 + d] = f2bf(acc);
  } else if (bid < 512){
    int d = bid-256; float acc = 0.f;
    for (int e=0;e<256;e++) acc += fc1w[d*256+e]*bf2f(tmpWk[c*256+e]);
    qkv2T[(256+c)*256 + d] = f2bf(acc);
  } else if (bid < 768){
    int d = bid-512; float acc = 0.f;
    for (int e=0;e<256;e++) acc += fc1w[d*256+e]*wv[e*256+c];
    qkv2T[(512+c)*256 + d] = f2bf(acc);
  } else {
    float aq=0.f, ak=0.f, av=0.f;
    for (int e=0;e<256;e++){
      float fb = fc1b[e];
      aq += fb*bf2f(tmpWq[c*256+e]);
      ak += fb*bf2f(tmpWk[c*256+e]);
      av += fb*wv[e*256+c];
    }
    cvec[c] = aq; cvec[256+c] = ak; cvec[512+c] = av;
  }
}

// ======== kNN: radix rank-select, 2 full scans (r13 version, 140 us) ========
__device__ __forceinline__ u32 fmap(float d){
  u32 u = __builtin_bit_cast(u32, d);
  return ((int)u < 0) ? ~u : (u | 0x80000000u);
}

__device__ __forceinline__ void find_thresh(const int* hist, int lane, int need,
                                            int* e_out, int* c_out){
  int h0 = hist[lane*4], h1 = hist[lane*4+1], h2 = hist[lane*4+2], h3 = hist[lane*4+3];
  int ps = h0 + h1 + h2 + h3;
  int incl = ps;
  #pragma unroll
  for (int d = 1; d < 64; d <<= 1){
    int tv = __shfl_up(incl, d, 64);
    if (lane >= d) incl += tv;
  }
  int excl = incl - ps;
  int b0 = excl, b1 = excl + h0, b2 = b1 + h1, b3 = b2 + h2;
  bool f0 = (b0 < need) && (b0 + h0 >= need);
  bool f1 = (b1 < need) && (b1 + h1 >= need);
  bool f2 = (b2 < need) && (b2 + h2 >= need);
  bool f3 = (b3 < need) && (b3 + h3 >= need);
  int e_loc = f0 ? lane*4 : f1 ? lane*4+1 : f2 ? lane*4+2 : lane*4+3;
  int c_loc = f0 ? b0 : f1 ? b1 : f2 ? b2 : b3;
  u64 mk = __ballot(f0 | f1 | f2 | f3);
  int wl = __ffsll(mk) - 1;
  *e_out = __shfl(e_loc, wl, 64);
  *c_out = __shfl(c_loc, wl, 64);
}

__device__ __forceinline__ void find_thresh4(const int* hA, int lane, int need,
                                             int* e_out, int* c_out){
  int h[4];
  #pragma unroll
  for (int j=0;j<4;j++){
    int bin = lane*4+j;
    h[j] = hA[bin]
         + hA[256 + ((bin+8)&255)]
         + hA[512 + ((bin+16)&255)]
         + hA[768 + ((bin+24)&255)];
  }
  int ps = h[0] + h[1] + h[2] + h[3];
  int incl = ps;
  #pragma unroll
  for (int d = 1; d < 64; d <<= 1){
    int tv = __shfl_up(incl, d, 64);
    if (lane >= d) incl += tv;
  }
  int excl = incl - ps;
  int b0 = excl, b1 = excl + h[0], b2 = b1 + h[1], b3 = b2 + h[2];
  bool f0 = (b0 < need) && (b0 + h[0] >= need);
  bool f1 = (b1 < need) && (b1 + h[1] >= need);
  bool f2 = (b2 < need) && (b2 + h[2] >= need);
  bool f3 = (b3 < need) && (b3 + h[3] >= need);
  int e_loc = f0 ? lane*4 : f1 ? lane*4+1 : f2 ? lane*4+2 : lane*4+3;
  int c_loc = f0 ? b0 : f1 ? b1 : f2 ? b2 : b3;
  u64 mk = __ballot(f0 | f1 | f2 | f3);
  int wl = __ffsll(mk) - 1;
  *e_out = __shfl(e_loc, wl, 64);
  *c_out = __shfl(c_loc, wl, 64);
}

__global__ __launch_bounds__(256) void k_knn(const float4* __restrict__ xyzw,
                                             int* __restrict__ gidxbuf,
                                             float4* __restrict__ relbuf){
  __shared__ int histA[4][1024];    // 16KB
  __shared__ int histB[4][256];     // 4KB

  int t = threadIdx.x, lane = t & 63, wv = t >> 6;
  int widx = blockIdx.x * 4 + wv;          // 0..16383
  int b = widx >> 12, n = widx & 4095;
  const float4* xb = xyzw + (size_t)b * NPTS;
  float4 P = xb[n];
  float x2n = P.w;
  int* hA = histA[wv]; int* hB = histB[wv];

  #pragma unroll
  for (int j = 0; j < 16; j++) hA[lane*16+j] = 0;
  #pragma unroll
  for (int j = 0; j < 4; j++)  hB[lane*4+j] = 0;
  wfence();

  int cp = lane >> 4;
  int cpoff = cp*256, cprot = cp*8;

  for (int it = 0; it < 64; it += 2){
    float4 Q0 = xb[it*64 + lane];
    float4 Q1 = xb[it*64 + 64 + lane];
    float d0 = x2n + Q0.w - 2.0f*(P.x*Q0.x + P.y*Q0.y + P.z*Q0.z);
    float d1 = x2n + Q1.w - 2.0f*(P.x*Q1.x + P.y*Q1.y + P.z*Q1.z);
    int b0 = (int)(fmap(d0) >> 24), b1 = (int)(fmap(d1) >> 24);
    atomicAdd(&hA[cpoff + ((b0 + cprot)&255)], 1);
    atomicAdd(&hA[cpoff + ((b1 + cprot)&255)], 1);
  }
  wfence();
  int e1, c0dummy;
  find_thresh4(hA, lane, 16, &e1, &c0dummy);
  wfence();

  u32* lstE_u = (u32*)&hA[0];
  int* lstE_m = &hA[128];
  u32* lstT_u = (u32*)&hA[256];
  int* lstT_m = &hA[320];

  int base = 0, Lc = 0;
  size_t orow = (size_t)widx * 16;
  for (int it = 0; it < 64; it++){
    int m = it*64 + lane;
    float4 Q = xb[m];
    u32 u = fmap(x2n + Q.w - 2.0f*(P.x*Q.x + P.y*Q.y + P.z*Q.z));
    int hi = (int)(u >> 24);
    bool def = hi < e1;
    bool bnd = hi == e1;
    u64 mkd = __ballot(def);
    if (def){
      int slot = base + __popcll(mkd & ((1ULL << lane) - 1ULL));
      gidxbuf[orow + slot] = b*NPTS + m;
      relbuf[orow + slot]  = make_float4(P.x - Q.x, P.y - Q.y, P.z - Q.z, 0.f);
    }
    base += __popcll(mkd);
    u64 mkb = __ballot(bnd);
    if (bnd){
      int sl = Lc + __popcll(mkb & ((1ULL << lane) - 1ULL));
      if (sl < 128){ lstE_u[sl] = u; lstE_m[sl] = m; }
      atomicAdd(&hB[(u >> 16) & 0xFF], 1);
    }
    Lc += __popcll(mkb);
  }
  wfence();
  int c0 = base;
  int m1, cc;
  find_thresh(hB, lane, 16 - c0, &m1, &cc);
  int c1 = c0 + cc;

  int nt = 0;
  if (Lc <= 128){
    int eb = c0;
    for (int ch = 0; ch < 128; ch += 64){
      int idx = ch + lane;
      bool valid = idx < Lc;
      u32 u = valid ? lstE_u[idx] : 0xFFFFFFFFu;
      int mid = valid ? (int)((u >> 16) & 0xFF) : 999;
      bool lt = valid && (mid < m1);
      u64 mk = __ballot(lt);
      if (lt){
        int slot = eb + __popcll(mk & ((1ULL << lane) - 1ULL));
        int m = lstE_m[idx];
        float4 Q = xb[m];
        gidxbuf[orow + slot] = b*NPTS + m;
        relbuf[orow + slot]  = make_float4(P.x - Q.x, P.y - Q.y, P.z - Q.z, 0.f);
      }
      eb += __popcll(mk);
      bool tie = valid && (mid == m1);
      u64 mkt = __ballot(tie);
      if (tie){
        int sl = nt + __popcll(mkt & ((1ULL << lane) - 1ULL));
        if (sl < 64){ lstT_u[sl] = u; lstT_m[sl] = lstE_m[idx]; }
      }
      nt += __popcll(mkt);
      if (Lc <= 64) break;
    }
  } else {
    int eb = c0;
    for (int it = 0; it < 64; it++){
      int m = it*64 + lane;
      float4 Q = xb[m];
      u32 u = fmap(x2n + Q.w - 2.0f*(P.x*Q.x + P.y*Q.y + P.z*Q.z));
      bool inb = ((int)(u >> 24) == e1);
      int mid = inb ? (int)((u >> 16) & 0xFF) : 999;
      bool lt = inb && (mid < m1);
      u64 mk = __ballot(lt);
      if (lt){
        int slot = eb + __popcll(mk & ((1ULL << lane) - 1ULL));
        gidxbuf[orow + slot] = b*NPTS + m;
        relbuf[orow + slot]  = make_float4(P.x - Q.x, P.y - Q.y, P.z - Q.z, 0.f);
      }
      eb += __popcll(mk);
      bool tie = inb && (mid == m1);
      u64 mkt = __ballot(tie);
      if (tie){
        int sl = nt + __popcll(mkt & ((1ULL << lane) - 1ULL));
        if (sl < 64){ lstT_u[sl] = u; lstT_m[sl] = m; }
      }
      nt += __popcll(mkt);
    }
  }
  wfence();
  if (nt > 64) nt = 64;

  int r2 = 16 - c1;
  u32 lu = (lane < nt) ? lstT_u[lane] : 0xFFFFFFFFu;
  int lm = (lane < nt) ? lstT_m[lane] : 0x7FFFFFFF;
  bool popped = false;
  for (int r = 0; r < r2; r++){
    u32 ku = popped ? 0xFFFFFFFFu : lu;
    int km = popped ? 0x7FFFFFFF : lm;
    #pragma unroll
    for (int off = 32; off >= 1; off >>= 1){
      u32 ou = __shfl_xor(ku, off, 64);
      int om = __shfl_xor(km, off, 64);
      if (ou < ku || (ou == ku && om < km)){ ku = ou; km = om; }
    }
    bool mine = !popped && (lane < nt) && (lu == ku) && (lm == km);
    u64 mk = __ballot(mine);
    int wl = __ffsll(mk) - 1;
    if (lane == wl){
      popped = true;
      float4 Q = xb[km];
      gidxbuf[orow + c1 + r] = b*NPTS + km;
      relbuf[orow + c1 + r]  = make_float4(P.x - Q.x, P.y - Q.y, P.z - Q.z, 0.f);
    }
  }
}

// ============ flat GEMM (512 thr, BM=128, BN=256): MODE 0 = QKV, MODE 4 = FIN ============
template<int MODE>
__global__ __launch_bounds__(512) void k_mm(
    const unsigned short* __restrict__ A, const unsigned short* __restrict__ BT,
    const float* __restrict__ bias,
    unsigned short* __restrict__ o0, unsigned short* __restrict__ o1,
    unsigned short* __restrict__ o2, unsigned short* __restrict__ o3,
    const unsigned short* __restrict__ scbuf, float* __restrict__ fout){
  __shared__ unsigned short As[4096];   // 128 x 32
  __shared__ unsigned short Bs[8192];   // 256 x 32
  __shared__ float  biasS[256];

  int t = threadIdx.x;
  int lane = t & 63, w = t >> 6;
  int wm = w >> 2, wn = w & 3;          // 2 x 4 wave grid
  int lrow = lane & 15, lkg = lane >> 4;
  int m0 = blockIdx.x * 128, n0 = blockIdx.y * 256;
  if (t < 256) biasS[t] = bias[n0 + t];

  int sr = t >> 2, sc = (t & 3) * 8;
  unsigned short* lA  = As + (w << 9);
  unsigned short* lB  = Bs + (w << 9);
  unsigned short* lB2 = Bs + 4096 + (w << 9);
  const unsigned short* gB  = BT + (size_t)(n0 + sr)*256 + sc;
  const unsigned short* gB2 = BT + (size_t)(n0 + 128 + sr)*256 + sc;

  f32x4 acc[4][4] = {};
  for (int k0 = 0; k0 < 256; k0 += 32){
    const unsigned short* gA = A + (size_t)(m0 + sr)*256 + k0 + sc;
    gl_lds16(gA, lA);
    gl_lds16(gB  + k0, lB);
    gl_lds16(gB2 + k0, lB2);
    __syncthreads();
    bf16x8 af[4], bfr[4];
    #pragma unroll
    for (int fi = 0; fi < 4; fi++)
      af[fi] = *(const bf16x8*)&As[(wm*64 + fi*16 + lrow)*32 + lkg*8];
    #pragma unroll
    for (int nf = 0; nf < 4; nf++)
      bfr[nf] = *(const bf16x8*)&Bs[(wn*64 + nf*16 + lrow)*32 + lkg*8];
    #pragma unroll
    for (int fi = 0; fi < 4; fi++)
      #pragma unroll
      for (int nf = 0; nf < 4; nf++)
        acc[fi][nf] = MFMA(af[fi], bfr[nf], acc[fi][nf]);
    __syncthreads();
  }

  if constexpr (MODE == 0){
    unsigned short* outp = (blockIdx.y==0)?o0:(blockIdx.y==1)?o1:(blockIdx.y==2)?o2:o3;
    #pragma unroll
    for (int fi=0; fi<4; fi++)
      #pragma unroll
      for (int nf=0; nf<4; nf++)
        #pragma unroll
        for (int r=0;r<4;r++){
          int row = m0 + wm*64 + fi*16 + lkg*4 + r;
          int col = wn*64 + nf*16 + lrow;
          outp[(size_t)row*256 + col] = f2bf(acc[fi][nf][r] + biasS[col]);
        }
  } else {   // FIN
    #pragma unroll
    for (int fi=0; fi<4; fi++)
      #pragma unroll
      for (int nf=0; nf<4; nf++)
        #pragma unroll
        for (int r=0;r<4;r++){
          int row = m0 + wm*64 + fi*16 + lkg*4 + r;
          int col = wn*64 + nf*16 + lrow;
          fout[(size_t)row*256 + col] = acc[fi][nf][r] + biasS[col]
                                      + bf2f(scbuf[(size_t)row*256 + col]);
        }
  }
}

// ============ fused G2a->G3->G2b: 256 thr (4 waves, 1x4), BM=64, BN=256 ============
// a1 tile lives in LDS (never hits HBM). Phases:
//  A: posg = H@W2g1; a1 = relu(posg + qg - kg + c1) -> a1s (swizzled)
//  B: s = a1s @ (g2/16); softmax over K=16 -> attn (overwrites acc3 regs)
//  C: pe = H@W2; res = sum_k attn*(pe + b2 + v[gidx])
// LDS 61696B -> 2 blocks/CU (barrier overlap across blocks).
__global__ __launch_bounds__(256) void k_fused(
    const unsigned short* __restrict__ BposT, const unsigned short* __restrict__ g2sT,
    const unsigned short* __restrict__ qg, const unsigned short* __restrict__ kg,
    const unsigned short* __restrict__ vb,
    const float4* __restrict__ relbuf, const int* __restrict__ gidxbuf,
    const float* __restrict__ W1, const float* __restrict__ b1d,
    const float* __restrict__ c1, const float* __restrict__ b2d,
    const float* __restrict__ gb2,
    unsigned short* __restrict__ res){
  extern __shared__ char smem[];
  char*           a1sB  = smem;                             // 32KB: 64 rows x 512B, swizzled
  unsigned short* As    = (unsigned short*)(smem + 32768);  // 4KB: 64x32 (H slices)
  unsigned short* Bs    = (unsigned short*)(smem + 36864);  // 16KB: 256x32
  float4*         W1s4  = (float4*)(smem + 53248);          // 4KB
  float4*         relS  = (float4*)(smem + 57344);          // 1KB
  int*            gidxS = (int*)(smem + 58368);             // 256B
  float*          c1s   = (float*)(smem + 58624);           // 1KB
  float*          b2s   = (float*)(smem + 59648);           // 1KB
  float*          gb2s  = (float*)(smem + 60672);           // 1KB -> total 61696

  int t = threadIdx.x;
  int lane = t & 63, w = t >> 6;        // 4 waves
  int wn = w;                           // wave owns cols [wn*64, wn*64+64)
  int lrow = lane & 15, lkg = lane >> 4;
  int bx = blockIdx.x;
  { int gx = gridDim.x; bx = (bx & 7) * (gx >> 3) + (bx >> 3); }   // XCD swizzle
  int m0 = bx * 64;                     // 4 points per block

  if (t < 64){
    relS[t]  = relbuf[(size_t)m0 + t];
    gidxS[t] = gidxbuf[(size_t)m0 + t];
  }
  W1s4[t] = make_float4(W1[t], W1[256+t], W1[512+t], b1d[t]);
  c1s[t] = c1[t]; b2s[t] = b2d[t]; gb2s[t] = gb2[t]*0.0625f;
  __syncthreads();
  float4 rl0 = relS[t >> 2];            // loop-invariant

  int sr = t >> 2, sc = (t & 3) * 8;    // staging coords (sr 0..63)
  // Bs quarter bases: quarter q rows [q*64, q*64+64); wave w lanes cover rows w*16..+16
  unsigned short* lBq[4];
  #pragma unroll
  for (int q = 0; q < 4; q++) lBq[q] = Bs + q*2048 + w*512;

  const unsigned short* BTa = BposT;                       // W2g1^T
  const unsigned short* BTb = g2sT;                        // (g2/16)^T
  const unsigned short* BTc = BposT + (size_t)256*256;     // W2^T

  // ---------------- phase A ----------------
  f32x4 acc[4][4] = {};
  for (int k0 = 0; k0 < 256; k0 += 32){
    { // H rows [0,64) cols [k0,k0+32)
      int r = sr, h = (t & 3) << 3;
      bf16x8 h0;
      #pragma unroll
      for (int j = 0; j < 8; j++){
        int c = k0 + h + j;
        float4 wa = W1s4[c];
        float x0 = rl0.x*wa.x + rl0.y*wa.y + rl0.z*wa.z + wa.w;
        h0[j] = (short)f2bfh(fmaxf(x0, 0.f));
      }
      *(bf16x8*)&As[r*32 + h] = h0;
    }
    #pragma unroll
    for (int q = 0; q < 4; q++)
      gl_lds16(BTa + (size_t)(q*64 + sr)*256 + k0 + sc, lBq[q]);
    __syncthreads();
    bf16x8 af[4], bfr[4];
    #pragma unroll
    for (int fi = 0; fi < 4; fi++)
      af[fi] = *(const bf16x8*)&As[(fi*16 + lrow)*32 + lkg*8];
    #pragma unroll
    for (int nf = 0; nf < 4; nf++)
      bfr[nf] = *(const bf16x8*)&Bs[(wn*64 + nf*16 + lrow)*32 + lkg*8];
    #pragma unroll
    for (int fi = 0; fi < 4; fi++)
      #pragma unroll
      for (int nf = 0; nf < 4; nf++)
        acc[fi][nf] = MFMA(af[fi], bfr[nf], acc[fi][nf]);
    __syncthreads();
  }
  // epilogue A: a1 -> a1s (swizzled)
  #pragma unroll
  for (int fi=0; fi<4; fi++){
    int g = (m0 >> 4) + fi;             // point id
    #pragma unroll
    for (int nf=0; nf<4; nf++){
      int colg = wn*64 + nf*16 + lrow;
      float qv = bf2f(qg[(size_t)g*256 + colg]) + c1s[colg];
      #pragma unroll
      for (int r=0;r<4;r++){
        int rl_ = fi*16 + lkg*4 + r;
        float a1 = acc[fi][nf][r] + qv - bf2f(kg[(size_t)gidxS[rl_]*256 + colg]);
        *(unsigned short*)(a1sB + swz(rl_, colg*2)) = f2bfh(fmaxf(a1, 0.f));
      }
    }
  }
  __syncthreads();                      // a1s visible

  // ---------------- phase B ----------------
  f32x4 acc3[4][4] = {};
  for (int k0 = 0; k0 < 256; k0 += 32){
    #pragma unroll
    for (int q = 0; q < 4; q++)
      gl_lds16(BTb + (size_t)(q*64 + sr)*256 + k0 + sc, lBq[q]);
    __syncthreads();
    bf16x8 af[4], bfr[4];
    #pragma unroll
    for (int fi = 0; fi < 4; fi++)
      af[fi] = *(const bf16x8*)(a1sB + swz(fi*16 + lrow, k0*2 + lkg*16));
    #pragma unroll
    for (int nf = 0; nf < 4; nf++)
      bfr[nf] = *(const bf16x8*)&Bs[(wn*64 + nf*16 + lrow)*32 + lkg*8];
    #pragma unroll
    for (int fi = 0; fi < 4; fi++)
      #pragma unroll
      for (int nf = 0; nf < 4; nf++)
        acc3[fi][nf] = MFMA(af[fi], bfr[nf], acc3[fi][nf]);
    __syncthreads();
  }
  // softmax per fragment (one point per fi; 16 rows = lkg*4+r over shfl 16/32)
  #pragma unroll
  for (int fi=0; fi<4; fi++)
    #pragma unroll
    for (int nf=0; nf<4; nf++){
      int colg = wn*64 + nf*16 + lrow;
      float s[4], e[4];
      #pragma unroll
      for (int r=0;r<4;r++) s[r] = acc3[fi][nf][r] + gb2s[colg];
      float mx = fmaxf(fmaxf(s[0],s[1]), fmaxf(s[2],s[3]));
      mx = fmaxf(mx, __shfl_xor(mx,16,64));
      mx = fmaxf(mx, __shfl_xor(mx,32,64));
      float sm = 0.f;
      #pragma unroll
      for (int r=0;r<4;r++){ e[r] = __expf(s[r]-mx); sm += e[r]; }
      sm += __shfl_xor(sm,16,64);
      sm += __shfl_xor(sm,32,64);
      float rs = 1.f/sm;
      #pragma unroll
      for (int r=0;r<4;r++) acc3[fi][nf][r] = e[r]*rs;   // attn in-place
    }

  // ---------------- phase C ----------------
  f32x4 acc2[4][4] = {};
  for (int k0 = 0; k0 < 256; k0 += 32){
    { // H again
      int r = sr, h = (t & 3) << 3;
      bf16x8 h0;
      #pragma unroll
      for (int j = 0; j < 8; j++){
        int c = k0 + h + j;
        float4 wa = W1s4[c];
        float x0 = rl0.x*wa.x + rl0.y*wa.y + rl0.z*wa.z + wa.w;
        h0[j] = (short)f2bfh(fmaxf(x0, 0.f));
      }
      *(bf16x8*)&As[r*32 + h] = h0;
    }
    #pragma unroll
    for (int q = 0; q < 4; q++)
      gl_lds16(BTc + (size_t)(q*64 + sr)*256 + k0 + sc, lBq[q]);
    __syncthreads();
    bf16x8 af[4], bfr[4];
    #pragma unroll
    for (int fi = 0; fi < 4; fi++)
      af[fi] = *(const bf16x8*)&As[(fi*16 + lrow)*32 + lkg*8];
    #pragma unroll
    for (int nf = 0; nf < 4; nf++)
      bfr[nf] = *(const bf16x8*)&Bs[(wn*64 + nf*16 + lrow)*32 + lkg*8];
    #pragma unroll
    for (int fi = 0; fi < 4; fi++)
      #pragma unroll
      for (int nf = 0; nf < 4; nf++)
        acc2[fi][nf] = MFMA(af[fi], bfr[nf], acc2[fi][nf]);
    __syncthreads();
  }
  // epilogue C: res = sum_k attn * (pe + b2 + v[gidx])
  #pragma unroll
  for (int fi=0; fi<4; fi++){
    int g = (m0 >> 4) + fi;
    #pragma unroll
    for (int nf=0; nf<4; nf++){
      int colg = wn*64 + nf*16 + lrow;
      float bb = b2s[colg];
      float tsum = 0.f;
      #pragma unroll
      for (int r=0;r<4;r++){
        int rl_ = fi*16 + lkg*4 + r;
        float vv = acc2[fi][nf][r] + bb + bf2f(vb[(size_t)gidxS[rl_]*256 + colg]);
        tsum += acc3[fi][nf][r] * vv;
      }
      tsum += __shfl_xor(tsum,16,64);
      tsum += __shfl_xor(tsum,32,64);
      if (lkg == 0) res[(size_t)g*256 + colg] = f2bf(tsum);
    }
  }
}

// ---------------- host ----------------
extern "C" void kernel_launch(void* const* d_in, const int* in_sizes, int n_in,
                              void* d_out, int out_size, void* d_ws, size_t ws_size,
                              hipStream_t stream){
  (void)in_sizes; (void)n_in; (void)out_size; (void)ws_size;
  const float* xyz  = (const float*)d_in[0];
  const float* feat = (const float*)d_in[1];
  const float* W1   = (const float*)d_in[2];
  const float* b1d  = (const float*)d_in[3];
  const float* W2   = (const float*)d_in[4];
  const float* b2d  = (const float*)d_in[5];
  const float* fc1w = (const float*)d_in[6];
  const float* fc1b = (const float*)d_in[7];
  const float* wq   = (const float*)d_in[8];
  const float* wk   = (const float*)d_in[9];
  const float* wv   = (const float*)d_in[10];
  const float* g1   = (const float*)d_in[11];
  const float* gb1  = (const float*)d_in[12];
  const float* g2   = (const float*)d_in[13];
  const float* gb2  = (const float*)d_in[14];
  const float* fc2w = (const float*)d_in[15];
  const float* fc2b = (const float*)d_in[16];
  const float* scw  = (const float*)d_in[17];
  const float* scb  = (const float*)d_in[18];

  char* ws = (char*)d_ws;
  size_t off = 0;
  auto alloc = [&](size_t bytes)->void*{ void* p = ws + off; off += (bytes + 255) & ~(size_t)255; return p; };
  unsigned short* Xb     = (unsigned short*)alloc((size_t)NTOT*256*2);  // reused as res
  unsigned short* qgb    = (unsigned short*)alloc((size_t)NTOT*256*2);
  unsigned short* kgb    = (unsigned short*)alloc((size_t)NTOT*256*2);
  unsigned short* vbb    = (unsigned short*)alloc((size_t)NTOT*256*2);
  unsigned short* scbuf  = (unsigned short*)alloc((size_t)NTOT*256*2);
  int*            gidxbuf= (int*)alloc((size_t)NROWS*4);
  float4*         relbuf = (float4*)alloc((size_t)NROWS*16);
  float4*         xyzw   = (float4*)alloc((size_t)NTOT*16);
  unsigned short* qkv2T  = (unsigned short*)alloc(1024*256*2);
  unsigned short* tmpWq  = (unsigned short*)alloc(256*256*2);
  unsigned short* tmpWk  = (unsigned short*)alloc(256*256*2);
  unsigned short* BposT  = (unsigned short*)alloc(512*256*2);
  unsigned short* g2sT   = (unsigned short*)alloc(256*256*2);
  unsigned short* fc2T   = (unsigned short*)alloc(256*256*2);
  float*          c1     = (float*)alloc(256*4);
  float*          cvec   = (float*)alloc(1024*4);
  unsigned short* res    = Xb;   // alias: Xb dead after k_mm<0>

  k_convert<<<4096, 256, 0, stream>>>(feat, Xb, NTOT*256);
  k_xyzw<<<64, 256, 0, stream>>>(xyz, xyzw);
  k_prep_mats<<<256, 256, 0, stream>>>(scw, g2, fc2w, W2, scb, qkv2T, g2sT, fc2T, BposT, cvec);
  k_prep_gemm<<<769, 256, 0, stream>>>(wq, wk, g1, W2, b2d, gb1, tmpWq, tmpWk, BposT, c1);
  k_prep_gemm2<<<769, 256, 0, stream>>>(fc1w, fc1b, wv, tmpWq, tmpWk, qkv2T, cvec);
  k_knn<<<4096, 256, 0, stream>>>(xyzw, gidxbuf, relbuf);

  k_mm<0><<<dim3(128, 4), 512, 0, stream>>>(Xb, qkv2T, cvec,
      qgb, kgb, vbb, scbuf, nullptr, nullptr);

  hipFuncSetAttribute((const void*)k_fused, hipFuncAttributeMaxDynamicSharedMemorySize, 61696);
  k_fused<<<dim3(NROWS/64), 256, 61696, stream>>>(BposT, g2sT, qgb, kgb, vbb,
      relbuf, gidxbuf, W1, b1d, c1, b2d, gb2, res);

  k_mm<4><<<dim3(128, 1), 512, 0, stream>>>(res, fc2T, fc2b,
      nullptr, nullptr, nullptr, nullptr, scbuf, (float*)d_out);
}